// Round 22
// baseline (471.848 us; speedup 1.0000x reference)
//
#include <hip/hip_runtime.h>
#include <hip/hip_bf16.h>
#include <math.h>

#define NPTS 16384
#define NE 4
#define NM 2048
#define DD 128    // D3
#define DP 64     // D1
#define NHE 256
#define NHM 256
#define NRES 64
#define NTK 16
#define NEG_INF -3.402823466e38f

typedef unsigned short u16;
typedef __attribute__((ext_vector_type(8))) short short8;
typedef __attribute__((ext_vector_type(4))) float f32x4;

// ---------- helpers ----------
__device__ __forceinline__ u16 f2bf(float x) {   // RNE float -> bf16 bits
  union { float f; unsigned u; } v; v.f = x;
  unsigned r = v.u + 0x7fffu + ((v.u >> 16) & 1u);
  return (u16)(r >> 16);
}
__device__ __forceinline__ float bf2f(u16 b) {
  union { float f; unsigned u; } v; v.u = ((unsigned)b) << 16;
  return v.f;
}
// monotone map: bf16 bits -> u16 with unsigned order == float order
__device__ __forceinline__ u16 bf2mono(u16 b) {
  return (u16)(b ^ ((b & 0x8000u) ? 0xFFFFu : 0x8000u));
}
__device__ __forceinline__ u16 mono2bf(u16 m) {
  return (u16)((m & 0x8000u) ? (m ^ 0x8000u) : (m ^ 0xFFFFu));
}

// ---------- kernel 1: per-point preproc (wave-aggregated routing, R13) ----------
__global__ __launch_bounds__(256) void k_preproc(
    const float* __restrict__ x, const float* __restrict__ lines,
    const float* __restrict__ Wm1, const float* __restrict__ bm1,
    const float* __restrict__ Wm2, const float* __restrict__ bm2,
    float* __restrict__ pf, float* __restrict__ pe,
    float* __restrict__ slotW, int* __restrict__ plist,
    int* __restrict__ pairE, int* __restrict__ pairS, int* __restrict__ cnt)
{
  int n = blockIdx.x * 256 + threadIdx.x;   // grid exact: all threads active
  int lane = threadIdx.x & 63;
  float c0 = x[n*5+0], c1 = x[n*5+1], c2 = x[n*5+2];

  float l0 = bm2[0], l1 = bm2[1], l2 = bm2[2], l3 = bm2[3];
#pragma unroll 4
  for (int j = 0; j < 64; ++j) {
    float h = fmaf(c0, Wm1[j], fmaf(c1, Wm1[64+j], fmaf(c2, Wm1[128+j], bm1[j])));
    h = fmaxf(h, 0.f);
    l0 = fmaf(h, Wm2[j*4+0], l0);
    l1 = fmaf(h, Wm2[j*4+1], l1);
    l2 = fmaf(h, Wm2[j*4+2], l2);
    l3 = fmaf(h, Wm2[j*4+3], l3);
  }
  float lg[4] = {l0, l1, l2, l3};
  float mx = fmaxf(fmaxf(l0, l1), fmaxf(l2, l3));
  float pr[4]; float ssum = 0.f;
#pragma unroll
  for (int k = 0; k < 4; ++k) { pr[k] = expf(lg[k] - mx); ssum += pr[k]; }
#pragma unroll
  for (int k = 0; k < 4; ++k) pr[k] /= ssum;
  int i0 = 0;
#pragma unroll
  for (int k = 1; k < 4; ++k) if (pr[k] > pr[i0]) i0 = k;
  int i1 = (i0 == 0) ? 1 : 0;
#pragma unroll
  for (int k = 0; k < 4; ++k) if (k != i0 && pr[k] > pr[i1]) i1 = k;
  float g0 = pr[i0], g1 = pr[i1], gs = g0 + g1;
  g0 /= gs; g1 /= gs;

  // wave-aggregated slot allocation
  int s0 = 0, s1 = 0;
  unsigned long long below = (1ull << lane) - 1ull;
#pragma unroll
  for (int ee = 0; ee < 4; ++ee) {
    unsigned long long m0 = __ballot(i0 == ee);
    unsigned long long m1 = __ballot(i1 == ee);
    int tot = __popcll(m0) + __popcll(m1);
    int base = 0;
    if (lane == 0 && tot > 0) base = atomicAdd(&cnt[ee], tot);
    base = __shfl(base, 0);
    if (i0 == ee) s0 = base + __popcll(m0 & below);
    if (i1 == ee) s1 = base + __popcll(m0) + __popcll(m1 & below);
  }
  plist[i0*NPTS + s0] = n; slotW[i0*NPTS + s0] = g0;
  plist[i1*NPTS + s1] = n; slotW[i1*NPTS + s1] = g1;
  pairE[n*2+0] = i0; pairE[n*2+1] = i1;
  pairS[n*2+0] = s0; pairS[n*2+1] = s1;

  pe[(size_t)n*64 + 0] = c0;
  pe[(size_t)n*64 + 1] = c1;
  pe[(size_t)n*64 + 2] = c2;
  float cc[3] = {c0, c1, c2};
#pragma unroll
  for (int i = 0; i < 10; ++i) {
    float sc = 3.14159274101257324f * (float)(1 << i);
#pragma unroll
    for (int j = 0; j < 3; ++j) {
      float a = sc * cc[j];
      pe[(size_t)n*64 + 3 + (i*3+j)*2 + 0] = sinf(a);
      pe[(size_t)n*64 + 3 + (i*3+j)*2 + 1] = cosf(a);
    }
  }
  pe[(size_t)n*64 + 63] = 0.f;

  float pfv[64];
#pragma unroll
  for (int d = 0; d < 64; ++d) pfv[d] = 1.f;
  for (int i = 0; i < 2; ++i) {
    float p = x[n*5 + 3 + i] * 63.0f;
    float f = floorf(p);
    float wfr = p - f;
    int j0 = (int)f;
    int j1 = (int)fminf(f + 1.0f, 63.0f);
    const float* L = lines + (size_t)i * 64 * 64;
#pragma unroll
    for (int d = 0; d < 64; ++d) {
      float a = L[d*64 + j0];
      float b = L[d*64 + j1];
      pfv[d] *= a + wfr * (b - a);
    }
  }
#pragma unroll
  for (int d = 0; d < 64; ++d) pf[(size_t)n*64 + d] = pfv[d];
}

// ---------- kernel 2: K/V projection ----------
__global__ __launch_bounds__(256) void k_kv(
    const float* __restrict__ mem_k, const float* __restrict__ mem_v,
    const float* __restrict__ Wk, const float* __restrict__ Wv,
    u16* __restrict__ Khf, float* __restrict__ Vhat)
{
  int e = blockIdx.y;
  int which = blockIdx.z;
  const float* src = which ? mem_v : mem_k;
  const float* W   = which ? Wv : Wk;
  int r0 = blockIdx.x * 32;
  __shared__ float sm[32][130];
  int tid = threadIdx.x;
  for (int idx = tid; idx < 32*32; idx += 256) {
    int r = idx >> 5, c4 = (idx & 31) * 4;
    float4 v = *(const float4*)(src + ((size_t)e*NM + r0 + r)*DD + c4);
    sm[r][c4+0] = v.x; sm[r][c4+1] = v.y; sm[r][c4+2] = v.z; sm[r][c4+3] = v.w;
  }
  __syncthreads();
  int r = tid >> 3, cb = (tid & 7) * 16;
  float acc[16];
#pragma unroll
  for (int i = 0; i < 16; ++i) acc[i] = 0.f;
  const float* We = W + (size_t)e*DD*DD;
#pragma unroll 4
  for (int k = 0; k < 128; ++k) {
    float s = sm[r][k];
    const float4* w4 = (const float4*)(We + (size_t)k*DD + cb);
#pragma unroll
    for (int q = 0; q < 4; ++q) {
      float4 wv = w4[q];
      acc[q*4+0] = fmaf(s, wv.x, acc[q*4+0]);
      acc[q*4+1] = fmaf(s, wv.y, acc[q*4+1]);
      acc[q*4+2] = fmaf(s, wv.z, acc[q*4+2]);
      acc[q*4+3] = fmaf(s, wv.w, acc[q*4+3]);
    }
  }
  if (which) {
    float* drow = Vhat + ((size_t)e*NM + r0 + r)*DD + cb;
#pragma unroll
    for (int i = 0; i < 16; ++i) drow[i] = acc[i];
  } else {
    int key = r0 + r;
    int T = key >> 4;
    int kr = key & 15;
#pragma unroll
    for (int b = 0; b < 2; ++b) {
      int k_off = cb + b*8;
      int kt = k_off >> 5;
      int lhi = (k_off >> 3) & 3;
      int lane_ = lhi*16 + kr;
      size_t dst = (((size_t)e*128 + T)*4 + kt)*512 + (size_t)lane_*8;
      unsigned ph[4];
#pragma unroll
      for (int p = 0; p < 4; ++p) {
        u16 h0 = f2bf(acc[b*8 + p*2 + 0]);
        u16 h1 = f2bf(acc[b*8 + p*2 + 1]);
        ph[p] = (unsigned)h0 | ((unsigned)h1 << 16);
      }
      *(uint4*)(Khf + dst) = make_uint4(ph[0], ph[1], ph[2], ph[3]);
    }
  }
}

// ---------- kernel 2v: VA1[e][key][64] = Vhat[e][key] @ A1[e][0:128] ----------
__global__ __launch_bounds__(256) void k_va1(
    const float* __restrict__ Vhat, const float* __restrict__ A1,
    float* __restrict__ VA1)
{
  int e = blockIdx.y;
  int r0 = blockIdx.x * 32;
  __shared__ float sm[32][130];
  int tid = threadIdx.x;
  for (int idx = tid; idx < 32*32; idx += 256) {
    int r = idx >> 5, c4 = (idx & 31) * 4;
    float4 v = *(const float4*)(Vhat + ((size_t)e*NM + r0 + r)*DD + c4);
    sm[r][c4+0] = v.x; sm[r][c4+1] = v.y; sm[r][c4+2] = v.z; sm[r][c4+3] = v.w;
  }
  __syncthreads();
  int r = tid >> 3, cb = (tid & 7) * 8;
  float acc[8];
#pragma unroll
  for (int i = 0; i < 8; ++i) acc[i] = 0.f;
  const float* Ae = A1 + (size_t)e*192*64;
#pragma unroll 4
  for (int k = 0; k < 128; ++k) {
    float s = sm[r][k];
    const float4* w4 = (const float4*)(Ae + (size_t)k*64 + cb);
    float4 w0 = w4[0], w1 = w4[1];
    acc[0] = fmaf(s, w0.x, acc[0]);
    acc[1] = fmaf(s, w0.y, acc[1]);
    acc[2] = fmaf(s, w0.z, acc[2]);
    acc[3] = fmaf(s, w0.w, acc[3]);
    acc[4] = fmaf(s, w1.x, acc[4]);
    acc[5] = fmaf(s, w1.y, acc[5]);
    acc[6] = fmaf(s, w1.z, acc[6]);
    acc[7] = fmaf(s, w1.w, acc[7]);
  }
  float* dst = VA1 + ((size_t)e*NM + r0 + r)*64 + cb;
  *(float4*)dst = make_float4(acc[0], acc[1], acc[2], acc[3]);
  *(float4*)(dst+4) = make_float4(acc[4], acc[5], acc[6], acc[7]);
}

// ---------- kernel 2b: pack per-expert weights into bf16 hi/lo B-fragments ----------
__global__ __launch_bounds__(64) void k_pack(
    const float* __restrict__ We1, const float* __restrict__ We2,
    const float* __restrict__ We3, const float* __restrict__ Wq,
    const float* __restrict__ A1, const float* __restrict__ A2,
    u16* __restrict__ We1h, u16* __restrict__ We1l,
    u16* __restrict__ We2h, u16* __restrict__ We2l,
    u16* __restrict__ We3h, u16* __restrict__ We3l,
    u16* __restrict__ Wqh,  u16* __restrict__ Wql,
    u16* __restrict__ A1h,  u16* __restrict__ A1l,
    u16* __restrict__ A2h,  u16* __restrict__ A2l)
{
  int e = blockIdx.y;
  int f = blockIdx.x;
  int lane = threadIdx.x;
  int col = lane & 15, khalf = lane >> 4;
  const float* src; u16 *dh, *dl;
  int Krows, N, ks, ct;
  if (f < 32) {
    int fl = f;        src = We1 + (size_t)e*63*256;  Krows = 63;  N = 256;
    ks = fl >> 4; ct = fl & 15;
    dh = We1h + ((size_t)e*32  + fl)*512; dl = We1l + ((size_t)e*32  + fl)*512;
  } else if (f < 160) {
    int fl = f - 32;   src = We2 + (size_t)e*256*256; Krows = 256; N = 256;
    ks = fl >> 4; ct = fl & 15;
    dh = We2h + ((size_t)e*128 + fl)*512; dl = We2l + ((size_t)e*128 + fl)*512;
  } else if (f < 224) {
    int fl = f - 160;  src = We3 + (size_t)e*256*128; Krows = 256; N = 128;
    ks = fl >> 3; ct = fl & 7;
    dh = We3h + ((size_t)e*64  + fl)*512; dl = We3l + ((size_t)e*64  + fl)*512;
  } else if (f < 256) {
    int fl = f - 224;  src = Wq  + (size_t)e*128*128; Krows = 128; N = 128;
    ks = fl >> 3; ct = fl & 7;
    dh = Wqh  + ((size_t)e*32  + fl)*512; dl = Wql  + ((size_t)e*32  + fl)*512;
  } else if (f < 280) {
    int fl = f - 256;  src = A1  + (size_t)e*192*64;  Krows = 192; N = 64;
    ks = fl >> 2; ct = fl & 3;
    dh = A1h  + ((size_t)e*24  + fl)*512; dl = A1l  + ((size_t)e*24  + fl)*512;
  } else {
    int fl = f - 280;  src = A2  + (size_t)e*64*128;  Krows = 64;  N = 128;
    ks = fl >> 3; ct = fl & 7;
    dh = A2h  + ((size_t)e*16  + fl)*512; dl = A2l  + ((size_t)e*16  + fl)*512;
  }
  unsigned ph[4], pl[4];
#pragma unroll
  for (int p = 0; p < 4; ++p) {
    int k0 = ks*32 + khalf*8 + 2*p;
    float x0 = (k0   < Krows) ? src[(size_t)k0*N     + ct*16 + col] : 0.f;
    float x1 = (k0+1 < Krows) ? src[(size_t)(k0+1)*N + ct*16 + col] : 0.f;
    u16 h0 = f2bf(x0), h1 = f2bf(x1);
    u16 l0 = f2bf(x0 - bf2f(h0)), l1 = f2bf(x1 - bf2f(h1));
    ph[p] = (unsigned)h0 | ((unsigned)h1 << 16);
    pl[p] = (unsigned)l0 | ((unsigned)l1 << 16);
  }
  *(uint4*)(dh + lane*8) = make_uint4(ph[0], ph[1], ph[2], ph[3]);
  *(uint4*)(dl + lane*8) = make_uint4(pl[0], pl[1], pl[2], pl[3]);
}

// ---------- kernel 2c: pack final-MLP weights M1/M2/M3 (shared, N=256) ----------
__global__ __launch_bounds__(64) void k_packM(
    const float* __restrict__ M1, const float* __restrict__ M2,
    const float* __restrict__ M3,
    u16* __restrict__ M1h, u16* __restrict__ M1l,
    u16* __restrict__ M2h, u16* __restrict__ M2l,
    u16* __restrict__ M3h, u16* __restrict__ M3l)
{
  int f = blockIdx.x;
  int lane = threadIdx.x;
  int col = lane & 15, khalf = lane >> 4;
  const float* src; u16 *dh, *dl;
  int ks, ct;
  if (f < 64)       { int fl=f;     src=M1; ks=fl>>4; ct=fl&15; dh=M1h+(size_t)fl*512; dl=M1l+(size_t)fl*512; }
  else if (f < 192) { int fl=f-64;  src=M2; ks=fl>>4; ct=fl&15; dh=M2h+(size_t)fl*512; dl=M2l+(size_t)fl*512; }
  else              { int fl=f-192; src=M3; ks=fl>>4; ct=fl&15; dh=M3h+(size_t)fl*512; dl=M3l+(size_t)fl*512; }
  unsigned ph[4], pl[4];
#pragma unroll
  for (int p = 0; p < 4; ++p) {
    int k0 = ks*32 + khalf*8 + 2*p;
    float x0 = src[(size_t)k0*NHM     + ct*16 + col];
    float x1 = src[(size_t)(k0+1)*NHM + ct*16 + col];
    u16 h0 = f2bf(x0), h1 = f2bf(x1);
    u16 l0 = f2bf(x0 - bf2f(h0)), l1 = f2bf(x1 - bf2f(h1));
    ph[p] = (unsigned)h0 | ((unsigned)h1 << 16);
    pl[p] = (unsigned)l0 | ((unsigned)l1 << 16);
  }
  *(uint4*)(dh + lane*8) = make_uint4(ph[0], ph[1], ph[2], ph[3]);
  *(uint4*)(dl + lane*8) = make_uint4(pl[0], pl[1], pl[2], pl[3]);
}

#define CONV_FRAG(PTR, AH, AL) {                                        \
    const float* p_ = (PTR);                                            \
    float4 u0_ = *(const float4*)p_, u1_ = *(const float4*)(p_+4);      \
    float xv_[8] = {u0_.x,u0_.y,u0_.z,u0_.w,u1_.x,u1_.y,u1_.z,u1_.w};   \
    union { unsigned u[4]; short8 s; } H_, L_;                          \
    _Pragma("unroll")                                                   \
    for (int q_ = 0; q_ < 4; ++q_) {                                    \
      u16 h0_ = f2bf(xv_[2*q_]), h1_ = f2bf(xv_[2*q_+1]);               \
      u16 l0_ = f2bf(xv_[2*q_] - bf2f(h0_));                            \
      u16 l1_ = f2bf(xv_[2*q_+1] - bf2f(h1_));                          \
      H_.u[q_] = (unsigned)h0_ | ((unsigned)h1_ << 16);                 \
      L_.u[q_] = (unsigned)l0_ | ((unsigned)l1_ << 16);                 \
    }                                                                   \
    AH = H_.s; AL = L_.s; }

// store one f32 value as hi/lo bf16 pair into actH/actL at index IDX
#define PUT_HL(IDX, F) { float f_ = (F); u16 h_ = f2bf(f_);             \
    actH[IDX] = h_; actL[IDX] = f2bf(f_ - bf2f(h_)); }

// ---------- kernel 3: MFMA expert SIREN MLP + LN + Q-proj ----------
// (R20: activations stored in LDS as pre-packed bf16 hi/lo.)
__global__ __launch_bounds__(256) void k_expert(
    const float* __restrict__ pe,
    const u16* __restrict__ We1h, const u16* __restrict__ We1l,
    const u16* __restrict__ We2h, const u16* __restrict__ We2l,
    const u16* __restrict__ We3h, const u16* __restrict__ We3l,
    const u16* __restrict__ Wqh,  const u16* __restrict__ Wql,
    const float* __restrict__ be1, const float* __restrict__ be2,
    const float* __restrict__ be3,
    const float* __restrict__ ln_g, const float* __restrict__ ln_b,
    const int* __restrict__ plist, const int* __restrict__ cnt,
    float* __restrict__ featsC, float* __restrict__ QC)
{
  int e = blockIdx.y;
  int count = cnt[e];
  int base = blockIdx.x * 32;
  if (base >= count) return;
  __shared__ u16 actH[16*512];   // 16 KB
  __shared__ u16 actL[16*512];   // 16 KB
  __shared__ float lnS[256];
  __shared__ int pts[32];
  int tid = threadIdx.x;
  int w = tid >> 6, lane = tid & 63;
  int rloc = lane & 15, khalf = lane >> 4;

  if (tid < 32) {
    int slot = base + tid;
    pts[tid] = (slot < count) ? plist[e*NPTS + slot] : 0;
  } else if (tid >= 64 && tid < 192) {
    int i = tid - 64;
    lnS[i] = ln_g[i];
    lnS[128 + i] = ln_b[i];
  }
  __syncthreads();
  {
    int Mt = tid >> 7, ks = (tid >> 6) & 1;
    const float* src = pe + (size_t)pts[Mt*16 + rloc]*64 + ks*32 + khalf*8;
    float4 a = *(const float4*)src;
    float4 b = *(const float4*)(src + 4);
    float xv[8] = {a.x,a.y,a.z,a.w,b.x,b.y,b.z,b.w};
    unsigned ph[4], pl[4];
#pragma unroll
    for (int q = 0; q < 4; ++q) {
      u16 h0 = f2bf(xv[2*q]), h1 = f2bf(xv[2*q+1]);
      u16 l0 = f2bf(xv[2*q] - bf2f(h0)), l1 = f2bf(xv[2*q+1] - bf2f(h1));
      ph[q] = (unsigned)h0 | ((unsigned)h1 << 16);
      pl[q] = (unsigned)l0 | ((unsigned)l1 << 16);
    }
    int idx = (Mt*8 + ks)*512 + lane*8;
    *(uint4*)&actH[idx] = make_uint4(ph[0], ph[1], ph[2], ph[3]);
    *(uint4*)&actL[idx] = make_uint4(pl[0], pl[1], pl[2], pl[3]);
  }
  __syncthreads();

  // ---- L1: K=64 (2 ks), N=256, sin(30x) ----
  {
    f32x4 acc[2][4];
#pragma unroll
    for (int Mt = 0; Mt < 2; ++Mt)
#pragma unroll
      for (int c = 0; c < 4; ++c) acc[Mt][c] = (f32x4){0.f,0.f,0.f,0.f};
    for (int ks = 0; ks < 2; ++ks) {
      short8 ah[2], al[2];
#pragma unroll
      for (int Mt = 0; Mt < 2; ++Mt) {
        int idx = (Mt*8+ks)*512 + lane*8;
        ah[Mt] = *(const short8*)&actH[idx];
        al[Mt] = *(const short8*)&actL[idx];
      }
#pragma unroll
      for (int c = 0; c < 4; ++c) {
        size_t fo = ((size_t)e*32 + ks*16 + w*4 + c)*512 + (size_t)lane*8;
        short8 bh = *(const short8*)(We1h + fo);
        short8 bl = *(const short8*)(We1l + fo);
#pragma unroll
        for (int Mt = 0; Mt < 2; ++Mt) {
          acc[Mt][c] = __builtin_amdgcn_mfma_f32_16x16x32_bf16(ah[Mt], bh, acc[Mt][c], 0,0,0);
          acc[Mt][c] = __builtin_amdgcn_mfma_f32_16x16x32_bf16(ah[Mt], bl, acc[Mt][c], 0,0,0);
          acc[Mt][c] = __builtin_amdgcn_mfma_f32_16x16x32_bf16(al[Mt], bh, acc[Mt][c], 0,0,0);
        }
      }
    }
    __syncthreads();
#pragma unroll
    for (int Mt = 0; Mt < 2; ++Mt)
#pragma unroll
      for (int c = 0; c < 4; ++c) {
        int n = (w*4+c)*16 + rloc;
        float b = be1[e*NHE + n];
        int ksp = n >> 5, lp = ((n>>3)&3)*16, jp = n & 7;
#pragma unroll
        for (int i = 0; i < 4; ++i) {
          int idx = (Mt*8+ksp)*512 + (lp + khalf*4 + i)*8 + jp;
          PUT_HL(idx, sinf(30.f*(acc[Mt][c][i] + b)));
        }
      }
    __syncthreads();
  }

  // ---- L2: K=256 (8 ks), N=256, sin(30x) ----
  {
    f32x4 acc[2][4];
#pragma unroll
    for (int Mt = 0; Mt < 2; ++Mt)
#pragma unroll
      for (int c = 0; c < 4; ++c) acc[Mt][c] = (f32x4){0.f,0.f,0.f,0.f};
#pragma unroll 2
    for (int ks = 0; ks < 8; ++ks) {
      short8 ah[2], al[2];
#pragma unroll
      for (int Mt = 0; Mt < 2; ++Mt) {
        int idx = (Mt*8+ks)*512 + lane*8;
        ah[Mt] = *(const short8*)&actH[idx];
        al[Mt] = *(const short8*)&actL[idx];
      }
#pragma unroll
      for (int c = 0; c < 4; ++c) {
        size_t fo = ((size_t)e*128 + ks*16 + w*4 + c)*512 + (size_t)lane*8;
        short8 bh = *(const short8*)(We2h + fo);
        short8 bl = *(const short8*)(We2l + fo);
#pragma unroll
        for (int Mt = 0; Mt < 2; ++Mt) {
          acc[Mt][c] = __builtin_amdgcn_mfma_f32_16x16x32_bf16(ah[Mt], bh, acc[Mt][c], 0,0,0);
          acc[Mt][c] = __builtin_amdgcn_mfma_f32_16x16x32_bf16(ah[Mt], bl, acc[Mt][c], 0,0,0);
          acc[Mt][c] = __builtin_amdgcn_mfma_f32_16x16x32_bf16(al[Mt], bh, acc[Mt][c], 0,0,0);
        }
      }
    }
    __syncthreads();
#pragma unroll
    for (int Mt = 0; Mt < 2; ++Mt)
#pragma unroll
      for (int c = 0; c < 4; ++c) {
        int n = (w*4+c)*16 + rloc;
        float b = be2[e*NHE + n];
        int ksp = n >> 5, lp = ((n>>3)&3)*16, jp = n & 7;
#pragma unroll
        for (int i = 0; i < 4; ++i) {
          int idx = (Mt*8+ksp)*512 + (lp + khalf*4 + i)*8 + jp;
          PUT_HL(idx, sinf(30.f*(acc[Mt][c][i] + b)));
        }
      }
    __syncthreads();
  }

  // ---- L3: K=256 (8 ks), N=128, linear -> feats ----
  {
    f32x4 acc[2][2];
#pragma unroll
    for (int Mt = 0; Mt < 2; ++Mt)
#pragma unroll
      for (int c = 0; c < 2; ++c) acc[Mt][c] = (f32x4){0.f,0.f,0.f,0.f};
#pragma unroll 2
    for (int ks = 0; ks < 8; ++ks) {
      short8 ah[2], al[2];
#pragma unroll
      for (int Mt = 0; Mt < 2; ++Mt) {
        int idx = (Mt*8+ks)*512 + lane*8;
        ah[Mt] = *(const short8*)&actH[idx];
        al[Mt] = *(const short8*)&actL[idx];
      }
#pragma unroll
      for (int c = 0; c < 2; ++c) {
        size_t fo = ((size_t)e*64 + ks*8 + w*2 + c)*512 + (size_t)lane*8;
        short8 bh = *(const short8*)(We3h + fo);
        short8 bl = *(const short8*)(We3l + fo);
#pragma unroll
        for (int Mt = 0; Mt < 2; ++Mt) {
          acc[Mt][c] = __builtin_amdgcn_mfma_f32_16x16x32_bf16(ah[Mt], bh, acc[Mt][c], 0,0,0);
          acc[Mt][c] = __builtin_amdgcn_mfma_f32_16x16x32_bf16(ah[Mt], bl, acc[Mt][c], 0,0,0);
          acc[Mt][c] = __builtin_amdgcn_mfma_f32_16x16x32_bf16(al[Mt], bh, acc[Mt][c], 0,0,0);
        }
      }
    }
    __syncthreads();
#pragma unroll
    for (int Mt = 0; Mt < 2; ++Mt)
#pragma unroll
      for (int c = 0; c < 2; ++c) {
        int n = (w*2+c)*16 + rloc;
        float b = be3[e*DD + n];
        int ksp = n >> 5, lp = ((n>>3)&3)*16, jp = n & 7;
#pragma unroll
        for (int i = 0; i < 4; ++i) {
          float f = acc[Mt][c][i] + b;
          int idx = (Mt*8+ksp)*512 + (lp + khalf*4 + i)*8 + jp;
          PUT_HL(idx, f);
          int slot = base + Mt*16 + khalf*4 + i;
          if (slot < count)
            featsC[((size_t)e*NPTS + slot)*DD + n] = f;
        }
      }
    __syncthreads();
  }

  // ---- LN + Wq: K=128 (4 ks), N=128 ----
  {
    float mu[2], rsv[2];
#pragma unroll
    for (int Mt = 0; Mt < 2; ++Mt) {
      float sm = 0.f, sq = 0.f;
#pragma unroll
      for (int ks = 0; ks < 4; ++ks) {
        int idx = (Mt*8+ks)*512 + lane*8;
        short8 hv = *(const short8*)&actH[idx];
        short8 lv = *(const short8*)&actL[idx];
#pragma unroll
        for (int j = 0; j < 8; ++j) {
          float xx = bf2f((u16)hv[j]) + bf2f((u16)lv[j]);
          sm += xx; sq += xx*xx;
        }
      }
      sm += __shfl_xor(sm, 16); sq += __shfl_xor(sq, 16);
      sm += __shfl_xor(sm, 32); sq += __shfl_xor(sq, 32);
      mu[Mt] = sm * (1.f/128.f);
      rsv[Mt] = rsqrtf(sq * (1.f/128.f) - mu[Mt]*mu[Mt] + 1e-5f);
    }
    f32x4 acc[2][2];
#pragma unroll
    for (int Mt = 0; Mt < 2; ++Mt)
#pragma unroll
      for (int c = 0; c < 2; ++c) acc[Mt][c] = (f32x4){0.f,0.f,0.f,0.f};
    for (int ks = 0; ks < 4; ++ks) {
      short8 ah[2], al[2];
#pragma unroll
      for (int Mt = 0; Mt < 2; ++Mt) {
        int idx = (Mt*8+ks)*512 + lane*8;
        short8 hv = *(const short8*)&actH[idx];
        short8 lv = *(const short8*)&actL[idx];
        float xv[8];
#pragma unroll
        for (int j = 0; j < 8; ++j)
          xv[j] = bf2f((u16)hv[j]) + bf2f((u16)lv[j]);
        union { unsigned u[4]; short8 s; } H, L;
#pragma unroll
        for (int j = 0; j < 8; ++j) {
          int k = ks*32 + khalf*8 + j;
          xv[j] = (xv[j] - mu[Mt]) * rsv[Mt] * lnS[k] + lnS[128 + k];
        }
#pragma unroll
        for (int q = 0; q < 4; ++q) {
          u16 h0 = f2bf(xv[2*q]), h1 = f2bf(xv[2*q+1]);
          u16 l0 = f2bf(xv[2*q] - bf2f(h0)), l1 = f2bf(xv[2*q+1] - bf2f(h1));
          H.u[q] = (unsigned)h0 | ((unsigned)h1 << 16);
          L.u[q] = (unsigned)l0 | ((unsigned)l1 << 16);
        }
        ah[Mt] = H.s; al[Mt] = L.s;
      }
#pragma unroll
      for (int c = 0; c < 2; ++c) {
        size_t fo = ((size_t)e*32 + ks*8 + w*2 + c)*512 + (size_t)lane*8;
        short8 bh = *(const short8*)(Wqh + fo);
        short8 bl = *(const short8*)(Wql + fo);
#pragma unroll
        for (int Mt = 0; Mt < 2; ++Mt) {
          acc[Mt][c] = __builtin_amdgcn_mfma_f32_16x16x32_bf16(ah[Mt], bh, acc[Mt][c], 0,0,0);
          acc[Mt][c] = __builtin_amdgcn_mfma_f32_16x16x32_bf16(ah[Mt], bl, acc[Mt][c], 0,0,0);
          acc[Mt][c] = __builtin_amdgcn_mfma_f32_16x16x32_bf16(al[Mt], bh, acc[Mt][c], 0,0,0);
        }
      }
    }
#pragma unroll
    for (int Mt = 0; Mt < 2; ++Mt)
#pragma unroll
      for (int c = 0; c < 2; ++c) {
        int n = (w*2+c)*16 + rloc;
#pragma unroll
        for (int i = 0; i < 4; ++i) {
          int slot = base + Mt*16 + khalf*4 + i;
          if (slot < count)
            QC[((size_t)e*NPTS + slot)*DD + n] = acc[Mt][c][i];
        }
      }
  }
}

// ---------- kernel 4: MFMA scores -> LDS score matrix -> register top-16 ----------
// R22: 1024-thread blocks, 32 slots, K-frag REUSE. Phase 1 was L2-read-bound
// (each 16-slot block streamed the expert's full 512 KB Khf -> 2 GB/dispatch
// ~ 58us at L2 BW). Each wave now holds TWO Q-frag sets (slot halves) and
// MFMAs every loaded K-frag against both -> K traffic per slot halved.
// Sall 32 rows = 128.5 KB LDS -> 1 block/CU, 16 waves = 4 waves/SIMD (TLP
// unchanged); phase 2 identical per-wave (2 slots, 2-wide ILP).
__global__ __launch_bounds__(1024) void k_scores(
    const float* __restrict__ QC, const u16* __restrict__ Khf,
    const int* __restrict__ cnt,
    float* __restrict__ attnW, int* __restrict__ attnI)
{
  int e = blockIdx.y;
  int count = cnt[e];
  int sbase = blockIdx.x * 32;
  if (sbase >= count) return;
  __shared__ u16 Sall[32*2056];   // [slot][key], padded row (128.5 KB)
  int tid = threadIdx.x;
  int w = tid >> 6, lane = tid & 63;
  int rloc = lane & 15, khalf = lane >> 4;

  // Q B-frags in registers for BOTH slot halves (same for all waves)
  short8 qf0[4], qf1[4];
#pragma unroll
  for (int h = 0; h < 2; ++h) {
    int slot = sbase + h*16 + rloc;
    const float* Qr = QC + ((size_t)e*NPTS + slot)*DD + khalf*8;
#pragma unroll
    for (int kt = 0; kt < 4; ++kt) {
      float q[8];
      if (slot < count) {
#pragma unroll
        for (int i = 0; i < 8; ++i) q[i] = Qr[kt*32 + i];
      } else {
#pragma unroll
        for (int i = 0; i < 8; ++i) q[i] = 0.f;
      }
      union { u16 h2[8]; short8 s; } U;
#pragma unroll
      for (int i = 0; i < 8; ++i) U.h2[i] = f2bf(q[i]);
      if (h == 0) qf0[kt] = U.s; else qf1[kt] = U.s;
    }
  }

  // ---- phase 1: all 2048 keys; wave w does key-tiles it*16+w, BOTH halves ----
  const u16* KhB = Khf + (size_t)e*128*4*512 + (size_t)lane*8;
  for (int it = 0; it < 8; ++it) {
    int T = it*16 + w;
    f32x4 acc0 = {0.f, 0.f, 0.f, 0.f};
    f32x4 acc1 = {0.f, 0.f, 0.f, 0.f};
#pragma unroll
    for (int kt = 0; kt < 4; ++kt) {
      short8 kf = *(const short8*)(KhB + ((size_t)T*4 + kt)*512);
      acc0 = __builtin_amdgcn_mfma_f32_16x16x32_bf16(kf, qf0[kt], acc0, 0, 0, 0);
      acc1 = __builtin_amdgcn_mfma_f32_16x16x32_bf16(kf, qf1[kt], acc1, 0, 0, 0);
    }
    union { u16 h[4]; ushort4 v; } P0, P1;
#pragma unroll
    for (int i = 0; i < 4; ++i) {
      P0.h[i] = bf2mono(f2bf(acc0[i]));
      P1.h[i] = bf2mono(f2bf(acc1[i]));
    }
    *(ushort4*)&Sall[(size_t)rloc*2056      + T*16 + khalf*4] = P0.v;
    *(ushort4*)&Sall[(size_t)(16+rloc)*2056 + T*16 + khalf*4] = P1.v;
  }
  __syncthreads();

  // ---- phase 2: wave w handles slots w*2 .. w*2+1, 2-wide interleaved ----
  const float inv_scale = 0.08838834764831845f;  // 1/sqrt(128)
#define INS4S(SL, P) { unsigned P_ = (P); if (P_ > p3[SL]) { p3[SL] = P_;       \
      if (p3[SL] > p2[SL]) { unsigned t_=p2[SL]; p2[SL]=p3[SL]; p3[SL]=t_; }    \
      if (p2[SL] > p1[SL]) { unsigned t_=p1[SL]; p1[SL]=p2[SL]; p2[SL]=t_; }    \
      if (p1[SL] > p0[SL]) { unsigned t_=p0[SL]; p0[SL]=p1[SL]; p1[SL]=t_; } } }

  {
    const u16* Srow[2];
    unsigned p0[2], p1[2], p2[2], p3[2];
#pragma unroll
    for (int sl = 0; sl < 2; ++sl) {
      Srow[sl] = &Sall[(size_t)(w*2 + sl)*2056];
      p0[sl] = p1[sl] = p2[sl] = p3[sl] = 0;
    }
    // interleaved candidate build: 2 rows' loads in flight together
#pragma unroll
    for (int i = 0; i < 16; ++i) {
      int k0 = lane*2 + i*128;
      unsigned cw[2];
#pragma unroll
      for (int sl = 0; sl < 2; ++sl)
        cw[sl] = *(const unsigned*)(Srow[sl] + k0);
#pragma unroll
      for (int sl = 0; sl < 2; ++sl) {
        unsigned P0 = ((cw[sl] & 0xFFFFu) << 11) | (unsigned)(2047 - k0);
        unsigned P1 = ((cw[sl] >> 16) << 11)     | (unsigned)(2047 - (k0+1));
        INS4S(sl, P0);
        INS4S(sl, P1);
      }
    }
    // 16 extraction rounds, 2 independent reduce chains per round
    unsigned keepP[2] = {0, 0};
    int popped[2] = {0, 0};
#pragma unroll 1
    for (int r = 0; r < 16; ++r) {
      unsigned m[2];
#pragma unroll
      for (int sl = 0; sl < 2; ++sl) m[sl] = p0[sl];
#pragma unroll
      for (int d = 1; d < 64; d <<= 1) {
#pragma unroll
        for (int sl = 0; sl < 2; ++sl) {
          unsigned o = __shfl_xor(m[sl], d);
          m[sl] = (o > m[sl]) ? o : m[sl];
        }
      }
#pragma unroll
      for (int sl = 0; sl < 2; ++sl) {
        if (lane == r) keepP[sl] = m[sl];
        if (p0[sl] == m[sl]) {   // unique winner (key embedded in packed value)
          p0[sl] = p1[sl]; p1[sl] = p2[sl]; p2[sl] = p3[sl]; p3[sl] = 0;
          if (++popped[sl] == 4) {
            // exact fallback: rebuild top-4 among remaining (< m strictly)
            p0[sl] = p1[sl] = p2[sl] = p3[sl] = 0;
            for (int i2 = 0; i2 < 16; ++i2) {
              int k0 = lane*2 + i2*128;
              unsigned cw = *(const unsigned*)(Srow[sl] + k0);
              unsigned P0 = ((cw & 0xFFFFu) << 11) | (unsigned)(2047 - k0);
              unsigned P1 = ((cw >> 16) << 11)     | (unsigned)(2047 - (k0+1));
              if (P0 < m[sl]) INS4S(sl, P0);
              if (P1 < m[sl]) INS4S(sl, P1);
            }
            popped[sl] = 0;
          }
        }
      }
    }
    // unpack + softmax + write (per slot; cheap)
#pragma unroll
    for (int sl = 0; sl < 2; ++sl) {
      int slot = sbase + w*2 + sl;
      if (slot >= count) continue;
      int keyv = 2047 - (int)(keepP[sl] & 0x7FFu);
      float val = bf2f(mono2bf((u16)(keepP[sl] >> 11)));
      float m0 = __shfl(val, 0);
      float ev = expf((val - m0) * inv_scale);
      float sum = ev;
      sum += __shfl_xor(sum, 1); sum += __shfl_xor(sum, 2);
      sum += __shfl_xor(sum, 4); sum += __shfl_xor(sum, 8);
      if (lane < 16) {
        size_t off = ((size_t)e*NPTS + slot)*NTK + lane;
        attnW[off] = ev / sum;
        attnI[off] = keyv;
      }
    }
  }
#undef INS4S
}

// ---------- kernel 5: MFMA adapter MLP + LN + attention combine ----------
// (R19: VA1 precompute; ainV out of LDS; 37.5 KB -> 4 blocks/CU.)
__global__ __launch_bounds__(256) void k_adapter(
    const float* __restrict__ Vhat, const float* __restrict__ pf,
    const float* __restrict__ VA1,
    const u16* __restrict__ A1h, const u16* __restrict__ A1l,
    const u16* __restrict__ A2h, const u16* __restrict__ A2l,
    const float* __restrict__ a1, const float* __restrict__ a2,
    const float* __restrict__ alng, const float* __restrict__ alnb,
    const float* __restrict__ attnW, const int* __restrict__ attnI,
    const float* __restrict__ featsC, const float* __restrict__ slotW,
    const int* __restrict__ plist, const int* __restrict__ cnt,
    float* __restrict__ outC)
{
  int e = blockIdx.y;
  int count = cnt[e];
  int s0 = blockIdx.x * 4;
  if (s0 >= count) return;
  __shared__ float hid[64][68];
  __shared__ float vaS[64][68];
  __shared__ float pfS[4][68];
  __shared__ float attwS[4][16];
  __shared__ float alnS[128], albS[128];
  __shared__ int   rtiS[64];
  __shared__ float wslS[4];
  __shared__ int   ptlS[4];
  int tid = threadIdx.x;
  if (tid < 64) {
    int sl = tid >> 4, key = tid & 15;
    int slot = s0 + sl;
    if (slot < count) {
      size_t o = ((size_t)e*NPTS + slot)*NTK + key;
      rtiS[tid] = attnI[o];
      attwS[sl][key] = attnW[o];
    } else { rtiS[tid] = 0; attwS[sl][key] = 0.f; }
  } else if (tid < 68) {
    int sl = tid - 64;
    int slot = s0 + sl;
    wslS[sl] = (slot < count) ? slotW[e*NPTS + slot] : 0.f;
    ptlS[sl] = (slot < count) ? plist[e*NPTS + slot] : 0;
  } else if (tid >= 128 && tid < 192) {
    int c2 = (tid - 128) * 2;
    alnS[c2]   = alng[e*DD + c2];
    alnS[c2+1] = alng[e*DD + c2+1];
    albS[c2]   = alnb[e*DD + c2];
    albS[c2+1] = alnb[e*DD + c2+1];
  }
  __syncthreads();
  // stage VA1 rows (64 x 64 f32) + pf rows
  for (int idx = tid; idx < 64*16; idx += 256) {
    int r = idx >> 4, c4 = (idx & 15) * 4;
    *(float4*)&vaS[r][c4] = *(const float4*)(VA1 + ((size_t)e*NM + rtiS[r])*64 + c4);
  }
  if (tid < 64) {
    int sl = tid >> 4, c4 = (tid & 15) * 4;
    *(float4*)&pfS[sl][c4] = *(const float4*)(pf + (size_t)ptlS[sl]*64 + c4);
  }
  __syncthreads();

  int w = tid >> 6, lane = tid & 63;
  int rloc = lane & 15;
  int khalf = lane >> 4;

  // ---- L1 (pf part only): K=64 (A1 frag ks=4,5), N=64 ----
  f32x4 acc1[4];
#pragma unroll
  for (int ct = 0; ct < 4; ++ct) acc1[ct] = (f32x4){0.f, 0.f, 0.f, 0.f};
  for (int ks = 4; ks < 6; ++ks) {
    short8 ah, al;
    CONV_FRAG(&pfS[w][(ks-4)*32 + khalf*8], ah, al);
    const u16* bh0 = A1h + ((size_t)e*24 + ks*4)*512 + (size_t)lane*8;
    const u16* bl0 = A1l + ((size_t)e*24 + ks*4)*512 + (size_t)lane*8;
#pragma unroll
    for (int ct = 0; ct < 4; ++ct) {
      short8 bh = *(const short8*)(bh0 + ct*512);
      short8 bl = *(const short8*)(bl0 + ct*512);
      acc1[ct] = __builtin_amdgcn_mfma_f32_16x16x32_bf16(ah, bh, acc1[ct], 0, 0, 0);
      acc1[ct] = __builtin_amdgcn_mfma_f32_16x16x32_bf16(ah, bl, acc1[ct], 0, 0, 0);
      acc1[ct] = __builtin_amdgcn_mfma_f32_16x16x32_bf16(al, bh, acc1[ct], 0, 0, 0);
    }
  }
#pragma unroll
  for (int ct = 0; ct < 4; ++ct) {
    float b = a1[e*64 + ct*16 + rloc];
#pragma unroll
    for (int i = 0; i < 4; ++i) {
      int row = w*16 + khalf*4 + i;
      hid[row][ct*16 + rloc] = fmaxf(acc1[ct][i] + b + vaS[row][ct*16 + rloc], 0.f);
    }
  }

  f32x4 acc2[8];
#pragma unroll
  for (int ct = 0; ct < 8; ++ct) acc2[ct] = (f32x4){0.f, 0.f, 0.f, 0.f};
  for (int ks = 0; ks < 2; ++ks) {
    short8 ah, al;
    CONV_FRAG(&hid[w*16 + rloc][ks*32 + khalf*8], ah, al);
    const u16* bh0 = A2h + ((size_t)e*16 + ks*8)*512 + (size_t)lane*8;
    const u16* bl0 = A2l + ((size_t)e*16 + ks*8)*512 + (size_t)lane*8;
#pragma unroll
    for (int ct = 0; ct < 8; ++ct) {
      short8 bh = *(const short8*)(bh0 + ct*512);
      short8 bl = *(const short8*)(bl0 + ct*512);
      acc2[ct] = __builtin_amdgcn_mfma_f32_16x16x32_bf16(ah, bh, acc2[ct], 0, 0, 0);
      acc2[ct] = __builtin_amdgcn_mfma_f32_16x16x32_bf16(ah, bl, acc2[ct], 0, 0, 0);
      acc2[ct] = __builtin_amdgcn_mfma_f32_16x16x32_bf16(al, bh, acc2[ct], 0, 0, 0);
    }
  }

  float ad[8][4];
#pragma unroll
  for (int ct = 0; ct < 8; ++ct) {
    float b = a2[e*DD + ct*16 + rloc];
#pragma unroll
    for (int i = 0; i < 4; ++i) ad[ct][i] = acc2[ct][i] + b;
  }
  float mu[4], rsv[4];
#pragma unroll
  for (int i = 0; i < 4; ++i) {
    float sm = 0.f, sq = 0.f;
#pragma unroll
    for (int ct = 0; ct < 8; ++ct) { sm += ad[ct][i]; sq += ad[ct][i]*ad[ct][i]; }
    sm += __shfl_xor(sm, 1); sq += __shfl_xor(sq, 1);
    sm += __shfl_xor(sm, 2); sq += __shfl_xor(sq, 2);
    sm += __shfl_xor(sm, 4); sq += __shfl_xor(sq, 4);
    sm += __shfl_xor(sm, 8); sq += __shfl_xor(sq, 8);
    mu[i] = sm * (1.f/128.f);
    float var = sq * (1.f/128.f) - mu[i]*mu[i];
    rsv[i] = rsqrtf(var + 1e-5f);
  }
  float aw[4];
#pragma unroll
  for (int i = 0; i < 4; ++i) aw[i] = attwS[w][khalf*4 + i];

  // combine: vt read direct from global (each element exactly once per block)
  const float* vrow[4];
#pragma unroll
  for (int i = 0; i < 4; ++i)
    vrow[i] = Vhat + ((size_t)e*NM + rtiS[w*16 + khalf*4 + i])*DD;

  float outv[8];
#pragma unroll
  for (int ct = 0; ct < 8; ++ct) {
    int cg = ct*16 + rloc;
    float g = alnS[cg], bb = albS[cg];
    float s = 0.f;
#pragma unroll
    for (int i = 0; i < 4; ++i) {
      float vt = vrow[i][cg];
      s += aw[i] * (vt + (ad[ct][i] - mu[i]) * rsv[i] * g + bb);
    }
    outv[ct] = s;
  }
#pragma unroll
  for (int ct = 0; ct < 8; ++ct) {
    outv[ct] += __shfl_xor(outv[ct], 16);
    outv[ct] += __shfl_xor(outv[ct], 32);
  }
  int slot = s0 + w;
  if (khalf == 0 && slot < count) {
    size_t o = ((size_t)e*NPTS + slot)*DD;
    float wg = wslS[w];
#pragma unroll
    for (int ct = 0; ct < 8; ++ct) {
      int cg = ct*16 + rloc;
      outC[o + cg] = wg * (outv[ct] + featsC[o + cg]);
    }
  }
}

// ---------- kernel 6: MFMA final MLP + sigmoid ----------
// (R21: actH/actL bf16 hi/lo packed activations.)
__global__ __launch_bounds__(256) void k_final(
    const float* __restrict__ outC, const int* __restrict__ pairE, const int* __restrict__ pairS,
    const u16* __restrict__ M1h, const u16* __restrict__ M1l,
    const u16* __restrict__ M2h, const u16* __restrict__ M2l,
    const u16* __restrict__ M3h, const u16* __restrict__ M3l,
    const float* __restrict__ c1, const float* __restrict__ c2,
    const float* __restrict__ c3,
    const float* __restrict__ M4, const float* __restrict__ c4,
    float* __restrict__ out)
{
  int base = blockIdx.x * 32;
  __shared__ u16 actH[16*512];   // 16 KB
  __shared__ u16 actL[16*512];   // 16 KB
  __shared__ float M4S[256];
  __shared__ int prE[64], prS[64];
  int tid = threadIdx.x;
  int w = tid >> 6, lane = tid & 63;
  int rloc = lane & 15, khalf = lane >> 4;

  if (tid < 64) {
    prE[tid] = pairE[(size_t)base*2 + tid];
    prS[tid] = pairS[(size_t)base*2 + tid];
  } else if (tid >= 64 && tid < 128) {
    int i = (tid - 64) * 4;
    *(float4*)&M4S[i] = *(const float4*)(M4 + i);
  }
  __syncthreads();
#pragma unroll
  for (int it = 0; it < 2; ++it) {
    int combo = it*4 + w;
    int Mt = combo >> 2, ks = combo & 3;
    int row = Mt*16 + rloc;
    const float* sA = outC + ((size_t)prE[row*2+0]*NPTS + prS[row*2+0])*DD + ks*32 + khalf*8;
    const float* sB = outC + ((size_t)prE[row*2+1]*NPTS + prS[row*2+1])*DD + ks*32 + khalf*8;
    float4 a0 = *(const float4*)sA, a1 = *(const float4*)(sA+4);
    float4 b0 = *(const float4*)sB, b1 = *(const float4*)(sB+4);
    float xv[8] = {a0.x+b0.x, a0.y+b0.y, a0.z+b0.z, a0.w+b0.w,
                   a1.x+b1.x, a1.y+b1.y, a1.z+b1.z, a1.w+b1.w};
    unsigned ph[4], pl[4];
#pragma unroll
    for (int q = 0; q < 4; ++q) {
      u16 h0 = f2bf(xv[2*q]), h1 = f2bf(xv[2*q+1]);
      u16 l0 = f2bf(xv[2*q] - bf2f(h0)), l1 = f2bf(xv[2*q+1] - bf2f(h1));
      ph[q] = (unsigned)h0 | ((unsigned)h1 << 16);
      pl[q] = (unsigned)l0 | ((unsigned)l1 << 16);
    }
    int idx = (Mt*8 + ks)*512 + lane*8;
    *(uint4*)&actH[idx] = make_uint4(ph[0], ph[1], ph[2], ph[3]);
    *(uint4*)&actL[idx] = make_uint4(pl[0], pl[1], pl[2], pl[3]);
  }
  __syncthreads();

  // ---- L1: K=128 (4 ks), N=256, relu ----
  {
    f32x4 acc[2][4];
#pragma unroll
    for (int Mt = 0; Mt < 2; ++Mt)
#pragma unroll
      for (int c = 0; c < 4; ++c) acc[Mt][c] = (f32x4){0.f,0.f,0.f,0.f};
    for (int ks = 0; ks < 4; ++ks) {
      short8 ah[2], al[2];
#pragma unroll
      for (int Mt = 0; Mt < 2; ++Mt) {
        int idx = (Mt*8+ks)*512 + lane*8;
        ah[Mt] = *(const short8*)&actH[idx];
        al[Mt] = *(const short8*)&actL[idx];
      }
#pragma unroll
      for (int c = 0; c < 4; ++c) {
        size_t fo = ((size_t)(ks*16 + w*4 + c))*512 + (size_t)lane*8;
        short8 bh = *(const short8*)(M1h + fo);
        short8 bl = *(const short8*)(M1l + fo);
#pragma unroll
        for (int Mt = 0; Mt < 2; ++Mt) {
          acc[Mt][c] = __builtin_amdgcn_mfma_f32_16x16x32_bf16(ah[Mt], bh, acc[Mt][c], 0,0,0);
          acc[Mt][c] = __builtin_amdgcn_mfma_f32_16x16x32_bf16(ah[Mt], bl, acc[Mt][c], 0,0,0);
          acc[Mt][c] = __builtin_amdgcn_mfma_f32_16x16x32_bf16(al[Mt], bh, acc[Mt][c], 0,0,0);
        }
      }
    }
    __syncthreads();
#pragma unroll
    for (int Mt = 0; Mt < 2; ++Mt)
#pragma unroll
      for (int c = 0; c < 4; ++c) {
        int n = (w*4+c)*16 + rloc;
        float b = c1[n];
        int ksp = n >> 5, lp = ((n>>3)&3)*16, jp = n & 7;
#pragma unroll
        for (int i = 0; i < 4; ++i) {
          int idx = (Mt*8+ksp)*512 + (lp + khalf*4 + i)*8 + jp;
          PUT_HL(idx, fmaxf(acc[Mt][c][i] + b, 0.f));
        }
      }
    __syncthreads();
  }

  // ---- L2, L3: K=256 (8 ks), N=256, relu ----
#pragma unroll 1
  for (int layer = 0; layer < 2; ++layer) {
    const u16* Wh = layer ? M3h : M2h;
    const u16* Wl = layer ? M3l : M2l;
    const float* bias = layer ? c3 : c2;
    f32x4 acc[2][4];
#pragma unroll
    for (int Mt = 0; Mt < 2; ++Mt)
#pragma unroll
      for (int c = 0; c < 4; ++c) acc[Mt][c] = (f32x4){0.f,0.f,0.f,0.f};
#pragma unroll 2
    for (int ks = 0; ks < 8; ++ks) {
      short8 ah[2], al[2];
#pragma unroll
      for (int Mt = 0; Mt < 2; ++Mt) {
        int idx = (Mt*8+ks)*512 + lane*8;
        ah[Mt] = *(const short8*)&actH[idx];
        al[Mt] = *(const short8*)&actL[idx];
      }
#pragma unroll
      for (int c = 0; c < 4; ++c) {
        size_t fo = ((size_t)(ks*16 + w*4 + c))*512 + (size_t)lane*8;
        short8 bh = *(const short8*)(Wh + fo);
        short8 bl = *(const short8*)(Wl + fo);
#pragma unroll
        for (int Mt = 0; Mt < 2; ++Mt) {
          acc[Mt][c] = __builtin_amdgcn_mfma_f32_16x16x32_bf16(ah[Mt], bh, acc[Mt][c], 0,0,0);
          acc[Mt][c] = __builtin_amdgcn_mfma_f32_16x16x32_bf16(ah[Mt], bl, acc[Mt][c], 0,0,0);
          acc[Mt][c] = __builtin_amdgcn_mfma_f32_16x16x32_bf16(al[Mt], bh, acc[Mt][c], 0,0,0);
        }
      }
    }
    __syncthreads();
#pragma unroll
    for (int Mt = 0; Mt < 2; ++Mt)
#pragma unroll
      for (int c = 0; c < 4; ++c) {
        int n = (w*4+c)*16 + rloc;
        float b = bias[n];
        int ksp = n >> 5, lp = ((n>>3)&3)*16, jp = n & 7;
#pragma unroll
        for (int i = 0; i < 4; ++i) {
          int idx = (Mt*8+ksp)*512 + (lp + khalf*4 + i)*8 + jp;
          PUT_HL(idx, fmaxf(acc[Mt][c][i] + b, 0.f));
        }
      }
    __syncthreads();
  }

  // ---- final: dot(row, M4) + c4 -> sigmoid; waves 0,1 handle Mt=w ----
  if (w < 2) {
    int Mt = w;
    float p = 0.f;
#pragma unroll
    for (int ks = 0; ks < 8; ++ks) {
      int idx = (Mt*8+ks)*512 + lane*8;
      short8 hv = *(const short8*)&actH[idx];
      short8 lv = *(const short8*)&actL[idx];
      const float* mm = &M4S[ks*32 + khalf*8];
#pragma unroll
      for (int j = 0; j < 8; ++j) {
        float xx = bf2f((u16)hv[j]) + bf2f((u16)lv[j]);
        p = fmaf(xx, mm[j], p);
      }
    }
    p += __shfl_xor(p, 16);
    p += __shfl_xor(p, 32);
    if (khalf == 0) {
      float z = p + c4[0];
      out[base + Mt*16 + rloc] = 1.f / (1.f + expf(-z));
    }
  }
}

// ---------- launcher ----------
extern "C" void kernel_launch(void* const* d_in, const int* in_sizes, int n_in,
                              void* d_out, int out_size, void* d_ws, size_t ws_size,
                              hipStream_t stream)
{
  const float* x    = (const float*)d_in[0];
  const float* lines= (const float*)d_in[1];
  const float* Wm1  = (const float*)d_in[2];
  const float* bm1  = (const float*)d_in[3];
  const float* Wm2  = (const float*)d_in[4];
  const float* bm2  = (const float*)d_in[5];
  const float* We1  = (const float*)d_in[6];
  const float* be1  = (const float*)d_in[7];
  const float* We2  = (const float*)d_in[8];
  const float* be2  = (const float*)d_in[9];
  const float* We3  = (const float*)d_in[10];
  const float* be3  = (const float*)d_in[11];
  const float* ln_g = (const float*)d_in[12];
  const float* ln_b = (const float*)d_in[13];
  const float* Wq   = (const float*)d_in[14];
  const float* Wk   = (const float*)d_in[15];
  const float* Wv   = (const float*)d_in[16];
  const float* A1   = (const float*)d_in[17];
  const float* a1   = (const float*)d_in[18];
  const float* A2   = (const float*)d_in[19];
  const float* a2   = (const float*)d_in[20];
  const float* alng = (const float*)d_in[21];
  const float* alnb = (const float*)d_in[22];
  const float* mem_k= (const float*)d_in[23];
  const float* mem_v= (const float*)d_in[24];
  const float* M1   = (const float*)d_in[25];
  const float* c1   = (const float*)d_in[26];
  const float* M2   = (const float*)d_in[27];
  const float* c2   = (const float*)d_in[28];
  const float* M3   = (const float*)d_in[29];
  const float* c3   = (const float*)d_in[30];
  const float* M4   = (const float*)d_in[31];
  const float* c4   = (const float*)d_in[32];
  float* out = (float*)d_out;

  char* wp = (char*)d_ws;
  auto alloc = [&](size_t bytes) -> void* {
    void* p = (void*)wp;
    wp += (bytes + 255) & ~(size_t)255;
    return p;
  };
  float* pf     = (float*)alloc((size_t)NPTS*64*4);
  float* pe     = (float*)alloc((size_t)NPTS*64*4);
  u16*   Khf    = (u16*)alloc((size_t)NE*128*4*512*2);   // bf16-hi K A-fragments
  u16*   We1h   = (u16*)alloc((size_t)NE*32*512*2);
  u16*   We1l   = (u16*)alloc((size_t)NE*32*512*2);
  u16*   We2h   = (u16*)alloc((size_t)NE*128*512*2);
  u16*   We2l   = (u16*)alloc((size_t)NE*128*512*2);
  u16*   We3h   = (u16*)alloc((size_t)NE*64*512*2);
  u16*   We3l   = (u16*)alloc((size_t)NE*64*512*2);
  u16*   Wqh    = (u16*)alloc((size_t)NE*32*512*2);
  u16*   Wql    = (u16*)alloc((size_t)NE*32*512*2);
  u16*   A1h    = (u16*)alloc((size_t)NE*24*512*2);
  u16*   A1l    = (u16*)alloc((size_t)NE*24*512*2);
  u16*   A2h    = (u16*)alloc((size_t)NE*16*512*2);
  u16*   A2l    = (u16*)alloc((size_t)NE*16*512*2);
  u16*   M1h    = (u16*)alloc((size_t)64*512*2);
  u16*   M1l    = (u16*)alloc((size_t)64*512*2);
  u16*   M2h    = (u16*)alloc((size_t)128*512*2);
  u16*   M2l    = (u16*)alloc((size_t)128*512*2);
  u16*   M3h    = (u16*)alloc((size_t)128*512*2);
  u16*   M3l    = (u16*)alloc((size_t)128*512*2);
  float* Vhat   = (float*)alloc((size_t)NE*NM*DD*4);
  float* VA1    = (float*)alloc((size_t)NE*NM*64*4);
  float* featsC = (float*)alloc((size_t)NE*NPTS*DD*4);
  float* QoutC  = (float*)alloc((size_t)NE*NPTS*DD*4);  // QC then reused as outC
  float* attnWb = (float*)alloc((size_t)NE*NPTS*NTK*4);
  float* slotW  = (float*)alloc((size_t)NE*NPTS*4);
  int*   attnIb = (int*)alloc((size_t)NE*NPTS*NTK*4);
  int*   plist  = (int*)alloc((size_t)NE*NPTS*4);
  int*   pairE  = (int*)alloc((size_t)NPTS*2*4);
  int*   pairS  = (int*)alloc((size_t)NPTS*2*4);
  int*   cnt    = (int*)alloc(64);

  hipMemsetAsync(cnt, 0, 64, stream);
  k_preproc<<<NPTS/256, 256, 0, stream>>>(x, lines, Wm1, bm1, Wm2, bm2,
                                          pf, pe, slotW, plist, pairE, pairS, cnt);
  k_kv<<<dim3(NM/32, NE, 2), 256, 0, stream>>>(mem_k, mem_v, Wk, Wv, Khf, Vhat);
  k_va1<<<dim3(NM/32, NE), 256, 0, stream>>>(Vhat, A1, VA1);
  k_pack<<<dim3(296, NE), 64, 0, stream>>>(We1, We2, We3, Wq, A1, A2,
                                           We1h, We1l, We2h, We2l,
                                           We3h, We3l, Wqh, Wql,
                                           A1h, A1l, A2h, A2l);
  k_packM<<<320, 64, 0, stream>>>(M1, M2, M3, M1h, M1l, M2h, M2l, M3h, M3l);
  k_expert<<<dim3(NPTS/32, NE), 256, 0, stream>>>(pe, We1h, We1l, We2h, We2l,
                                                  We3h, We3l, Wqh, Wql,
                                                  be1, be2, be3, ln_g, ln_b,
                                                  plist, cnt, featsC, QoutC);
  k_scores<<<dim3(NPTS/32, NE), 1024, 0, stream>>>(QoutC, Khf, cnt, attnWb, attnIb);
  k_adapter<<<dim3(NPTS/4, NE), 256, 0, stream>>>(Vhat, pf, VA1, A1h, A1l, A2h, A2l,
                                                  a1, a2, alng, alnb,
                                                  attnWb, attnIb, featsC, slotW, plist, cnt,
                                                  QoutC);
  k_final<<<NPTS/32, 256, 0, stream>>>(QoutC, pairE, pairS,
                                       M1h, M1l, M2h, M2l, M3h, M3l,
                                       c1, c2, c3, M4, c4, out);
}

// Round 23
// 438.747 us; speedup vs baseline: 1.0754x; 1.0754x over previous
//
#include <hip/hip_runtime.h>
#include <hip/hip_bf16.h>
#include <math.h>

#define NPTS 16384
#define NE 4
#define NM 2048
#define DD 128    // D3
#define DP 64     // D1
#define NHE 256
#define NHM 256
#define NRES 64
#define NTK 16
#define NEG_INF -3.402823466e38f

typedef unsigned short u16;
typedef __attribute__((ext_vector_type(8))) short short8;
typedef __attribute__((ext_vector_type(4))) float f32x4;

// ---------- helpers ----------
__device__ __forceinline__ u16 f2bf(float x) {   // RNE float -> bf16 bits
  union { float f; unsigned u; } v; v.f = x;
  unsigned r = v.u + 0x7fffu + ((v.u >> 16) & 1u);
  return (u16)(r >> 16);
}
__device__ __forceinline__ float bf2f(u16 b) {
  union { float f; unsigned u; } v; v.u = ((unsigned)b) << 16;
  return v.f;
}
// monotone map: bf16 bits -> u16 with unsigned order == float order
__device__ __forceinline__ u16 bf2mono(u16 b) {
  return (u16)(b ^ ((b & 0x8000u) ? 0xFFFFu : 0x8000u));
}
__device__ __forceinline__ u16 mono2bf(u16 m) {
  return (u16)((m & 0x8000u) ? (m ^ 0x8000u) : (m ^ 0xFFFFu));
}

// ---------- kernel 1: per-point preproc (wave-aggregated routing, R13) ----------
__global__ __launch_bounds__(256) void k_preproc(
    const float* __restrict__ x, const float* __restrict__ lines,
    const float* __restrict__ Wm1, const float* __restrict__ bm1,
    const float* __restrict__ Wm2, const float* __restrict__ bm2,
    float* __restrict__ pf, float* __restrict__ pe,
    float* __restrict__ slotW, int* __restrict__ plist,
    int* __restrict__ pairE, int* __restrict__ pairS, int* __restrict__ cnt)
{
  int n = blockIdx.x * 256 + threadIdx.x;   // grid exact: all threads active
  int lane = threadIdx.x & 63;
  float c0 = x[n*5+0], c1 = x[n*5+1], c2 = x[n*5+2];

  float l0 = bm2[0], l1 = bm2[1], l2 = bm2[2], l3 = bm2[3];
#pragma unroll 4
  for (int j = 0; j < 64; ++j) {
    float h = fmaf(c0, Wm1[j], fmaf(c1, Wm1[64+j], fmaf(c2, Wm1[128+j], bm1[j])));
    h = fmaxf(h, 0.f);
    l0 = fmaf(h, Wm2[j*4+0], l0);
    l1 = fmaf(h, Wm2[j*4+1], l1);
    l2 = fmaf(h, Wm2[j*4+2], l2);
    l3 = fmaf(h, Wm2[j*4+3], l3);
  }
  float lg[4] = {l0, l1, l2, l3};
  float mx = fmaxf(fmaxf(l0, l1), fmaxf(l2, l3));
  float pr[4]; float ssum = 0.f;
#pragma unroll
  for (int k = 0; k < 4; ++k) { pr[k] = expf(lg[k] - mx); ssum += pr[k]; }
#pragma unroll
  for (int k = 0; k < 4; ++k) pr[k] /= ssum;
  int i0 = 0;
#pragma unroll
  for (int k = 1; k < 4; ++k) if (pr[k] > pr[i0]) i0 = k;
  int i1 = (i0 == 0) ? 1 : 0;
#pragma unroll
  for (int k = 0; k < 4; ++k) if (k != i0 && pr[k] > pr[i1]) i1 = k;
  float g0 = pr[i0], g1 = pr[i1], gs = g0 + g1;
  g0 /= gs; g1 /= gs;

  // wave-aggregated slot allocation
  int s0 = 0, s1 = 0;
  unsigned long long below = (1ull << lane) - 1ull;
#pragma unroll
  for (int ee = 0; ee < 4; ++ee) {
    unsigned long long m0 = __ballot(i0 == ee);
    unsigned long long m1 = __ballot(i1 == ee);
    int tot = __popcll(m0) + __popcll(m1);
    int base = 0;
    if (lane == 0 && tot > 0) base = atomicAdd(&cnt[ee], tot);
    base = __shfl(base, 0);
    if (i0 == ee) s0 = base + __popcll(m0 & below);
    if (i1 == ee) s1 = base + __popcll(m0) + __popcll(m1 & below);
  }
  plist[i0*NPTS + s0] = n; slotW[i0*NPTS + s0] = g0;
  plist[i1*NPTS + s1] = n; slotW[i1*NPTS + s1] = g1;
  pairE[n*2+0] = i0; pairE[n*2+1] = i1;
  pairS[n*2+0] = s0; pairS[n*2+1] = s1;

  pe[(size_t)n*64 + 0] = c0;
  pe[(size_t)n*64 + 1] = c1;
  pe[(size_t)n*64 + 2] = c2;
  float cc[3] = {c0, c1, c2};
#pragma unroll
  for (int i = 0; i < 10; ++i) {
    float sc = 3.14159274101257324f * (float)(1 << i);
#pragma unroll
    for (int j = 0; j < 3; ++j) {
      float a = sc * cc[j];
      pe[(size_t)n*64 + 3 + (i*3+j)*2 + 0] = sinf(a);
      pe[(size_t)n*64 + 3 + (i*3+j)*2 + 1] = cosf(a);
    }
  }
  pe[(size_t)n*64 + 63] = 0.f;

  float pfv[64];
#pragma unroll
  for (int d = 0; d < 64; ++d) pfv[d] = 1.f;
  for (int i = 0; i < 2; ++i) {
    float p = x[n*5 + 3 + i] * 63.0f;
    float f = floorf(p);
    float wfr = p - f;
    int j0 = (int)f;
    int j1 = (int)fminf(f + 1.0f, 63.0f);
    const float* L = lines + (size_t)i * 64 * 64;
#pragma unroll
    for (int d = 0; d < 64; ++d) {
      float a = L[d*64 + j0];
      float b = L[d*64 + j1];
      pfv[d] *= a + wfr * (b - a);
    }
  }
#pragma unroll
  for (int d = 0; d < 64; ++d) pf[(size_t)n*64 + d] = pfv[d];
}

// ---------- kernel 2: K/V projection ----------
__global__ __launch_bounds__(256) void k_kv(
    const float* __restrict__ mem_k, const float* __restrict__ mem_v,
    const float* __restrict__ Wk, const float* __restrict__ Wv,
    u16* __restrict__ Khf, float* __restrict__ Vhat)
{
  int e = blockIdx.y;
  int which = blockIdx.z;
  const float* src = which ? mem_v : mem_k;
  const float* W   = which ? Wv : Wk;
  int r0 = blockIdx.x * 32;
  __shared__ float sm[32][130];
  int tid = threadIdx.x;
  for (int idx = tid; idx < 32*32; idx += 256) {
    int r = idx >> 5, c4 = (idx & 31) * 4;
    float4 v = *(const float4*)(src + ((size_t)e*NM + r0 + r)*DD + c4);
    sm[r][c4+0] = v.x; sm[r][c4+1] = v.y; sm[r][c4+2] = v.z; sm[r][c4+3] = v.w;
  }
  __syncthreads();
  int r = tid >> 3, cb = (tid & 7) * 16;
  float acc[16];
#pragma unroll
  for (int i = 0; i < 16; ++i) acc[i] = 0.f;
  const float* We = W + (size_t)e*DD*DD;
#pragma unroll 4
  for (int k = 0; k < 128; ++k) {
    float s = sm[r][k];
    const float4* w4 = (const float4*)(We + (size_t)k*DD + cb);
#pragma unroll
    for (int q = 0; q < 4; ++q) {
      float4 wv = w4[q];
      acc[q*4+0] = fmaf(s, wv.x, acc[q*4+0]);
      acc[q*4+1] = fmaf(s, wv.y, acc[q*4+1]);
      acc[q*4+2] = fmaf(s, wv.z, acc[q*4+2]);
      acc[q*4+3] = fmaf(s, wv.w, acc[q*4+3]);
    }
  }
  if (which) {
    float* drow = Vhat + ((size_t)e*NM + r0 + r)*DD + cb;
#pragma unroll
    for (int i = 0; i < 16; ++i) drow[i] = acc[i];
  } else {
    int key = r0 + r;
    int T = key >> 4;
    int kr = key & 15;
#pragma unroll
    for (int b = 0; b < 2; ++b) {
      int k_off = cb + b*8;
      int kt = k_off >> 5;
      int lhi = (k_off >> 3) & 3;
      int lane_ = lhi*16 + kr;
      size_t dst = (((size_t)e*128 + T)*4 + kt)*512 + (size_t)lane_*8;
      unsigned ph[4];
#pragma unroll
      for (int p = 0; p < 4; ++p) {
        u16 h0 = f2bf(acc[b*8 + p*2 + 0]);
        u16 h1 = f2bf(acc[b*8 + p*2 + 1]);
        ph[p] = (unsigned)h0 | ((unsigned)h1 << 16);
      }
      *(uint4*)(Khf + dst) = make_uint4(ph[0], ph[1], ph[2], ph[3]);
    }
  }
}

// ---------- kernel 2v: VA1[e][key][64] = Vhat[e][key] @ A1[e][0:128] ----------
__global__ __launch_bounds__(256) void k_va1(
    const float* __restrict__ Vhat, const float* __restrict__ A1,
    float* __restrict__ VA1)
{
  int e = blockIdx.y;
  int r0 = blockIdx.x * 32;
  __shared__ float sm[32][130];
  int tid = threadIdx.x;
  for (int idx = tid; idx < 32*32; idx += 256) {
    int r = idx >> 5, c4 = (idx & 31) * 4;
    float4 v = *(const float4*)(Vhat + ((size_t)e*NM + r0 + r)*DD + c4);
    sm[r][c4+0] = v.x; sm[r][c4+1] = v.y; sm[r][c4+2] = v.z; sm[r][c4+3] = v.w;
  }
  __syncthreads();
  int r = tid >> 3, cb = (tid & 7) * 8;
  float acc[8];
#pragma unroll
  for (int i = 0; i < 8; ++i) acc[i] = 0.f;
  const float* Ae = A1 + (size_t)e*192*64;
#pragma unroll 4
  for (int k = 0; k < 128; ++k) {
    float s = sm[r][k];
    const float4* w4 = (const float4*)(Ae + (size_t)k*64 + cb);
    float4 w0 = w4[0], w1 = w4[1];
    acc[0] = fmaf(s, w0.x, acc[0]);
    acc[1] = fmaf(s, w0.y, acc[1]);
    acc[2] = fmaf(s, w0.z, acc[2]);
    acc[3] = fmaf(s, w0.w, acc[3]);
    acc[4] = fmaf(s, w1.x, acc[4]);
    acc[5] = fmaf(s, w1.y, acc[5]);
    acc[6] = fmaf(s, w1.z, acc[6]);
    acc[7] = fmaf(s, w1.w, acc[7]);
  }
  float* dst = VA1 + ((size_t)e*NM + r0 + r)*64 + cb;
  *(float4*)dst = make_float4(acc[0], acc[1], acc[2], acc[3]);
  *(float4*)(dst+4) = make_float4(acc[4], acc[5], acc[6], acc[7]);
}

// ---------- kernel 2b: pack per-expert weights into bf16 hi/lo B-fragments ----------
__global__ __launch_bounds__(64) void k_pack(
    const float* __restrict__ We1, const float* __restrict__ We2,
    const float* __restrict__ We3, const float* __restrict__ Wq,
    const float* __restrict__ A1, const float* __restrict__ A2,
    u16* __restrict__ We1h, u16* __restrict__ We1l,
    u16* __restrict__ We2h, u16* __restrict__ We2l,
    u16* __restrict__ We3h, u16* __restrict__ We3l,
    u16* __restrict__ Wqh,  u16* __restrict__ Wql,
    u16* __restrict__ A1h,  u16* __restrict__ A1l,
    u16* __restrict__ A2h,  u16* __restrict__ A2l)
{
  int e = blockIdx.y;
  int f = blockIdx.x;
  int lane = threadIdx.x;
  int col = lane & 15, khalf = lane >> 4;
  const float* src; u16 *dh, *dl;
  int Krows, N, ks, ct;
  if (f < 32) {
    int fl = f;        src = We1 + (size_t)e*63*256;  Krows = 63;  N = 256;
    ks = fl >> 4; ct = fl & 15;
    dh = We1h + ((size_t)e*32  + fl)*512; dl = We1l + ((size_t)e*32  + fl)*512;
  } else if (f < 160) {
    int fl = f - 32;   src = We2 + (size_t)e*256*256; Krows = 256; N = 256;
    ks = fl >> 4; ct = fl & 15;
    dh = We2h + ((size_t)e*128 + fl)*512; dl = We2l + ((size_t)e*128 + fl)*512;
  } else if (f < 224) {
    int fl = f - 160;  src = We3 + (size_t)e*256*128; Krows = 256; N = 128;
    ks = fl >> 3; ct = fl & 7;
    dh = We3h + ((size_t)e*64  + fl)*512; dl = We3l + ((size_t)e*64  + fl)*512;
  } else if (f < 256) {
    int fl = f - 224;  src = Wq  + (size_t)e*128*128; Krows = 128; N = 128;
    ks = fl >> 3; ct = fl & 7;
    dh = Wqh  + ((size_t)e*32  + fl)*512; dl = Wql  + ((size_t)e*32  + fl)*512;
  } else if (f < 280) {
    int fl = f - 256;  src = A1  + (size_t)e*192*64;  Krows = 192; N = 64;
    ks = fl >> 2; ct = fl & 3;
    dh = A1h  + ((size_t)e*24  + fl)*512; dl = A1l  + ((size_t)e*24  + fl)*512;
  } else {
    int fl = f - 280;  src = A2  + (size_t)e*64*128;  Krows = 64;  N = 128;
    ks = fl >> 3; ct = fl & 7;
    dh = A2h  + ((size_t)e*16  + fl)*512; dl = A2l  + ((size_t)e*16  + fl)*512;
  }
  unsigned ph[4], pl[4];
#pragma unroll
  for (int p = 0; p < 4; ++p) {
    int k0 = ks*32 + khalf*8 + 2*p;
    float x0 = (k0   < Krows) ? src[(size_t)k0*N     + ct*16 + col] : 0.f;
    float x1 = (k0+1 < Krows) ? src[(size_t)(k0+1)*N + ct*16 + col] : 0.f;
    u16 h0 = f2bf(x0), h1 = f2bf(x1);
    u16 l0 = f2bf(x0 - bf2f(h0)), l1 = f2bf(x1 - bf2f(h1));
    ph[p] = (unsigned)h0 | ((unsigned)h1 << 16);
    pl[p] = (unsigned)l0 | ((unsigned)l1 << 16);
  }
  *(uint4*)(dh + lane*8) = make_uint4(ph[0], ph[1], ph[2], ph[3]);
  *(uint4*)(dl + lane*8) = make_uint4(pl[0], pl[1], pl[2], pl[3]);
}

// ---------- kernel 2c: pack final-MLP weights M1/M2/M3 (shared, N=256) ----------
__global__ __launch_bounds__(64) void k_packM(
    const float* __restrict__ M1, const float* __restrict__ M2,
    const float* __restrict__ M3,
    u16* __restrict__ M1h, u16* __restrict__ M1l,
    u16* __restrict__ M2h, u16* __restrict__ M2l,
    u16* __restrict__ M3h, u16* __restrict__ M3l)
{
  int f = blockIdx.x;
  int lane = threadIdx.x;
  int col = lane & 15, khalf = lane >> 4;
  const float* src; u16 *dh, *dl;
  int ks, ct;
  if (f < 64)       { int fl=f;     src=M1; ks=fl>>4; ct=fl&15; dh=M1h+(size_t)fl*512; dl=M1l+(size_t)fl*512; }
  else if (f < 192) { int fl=f-64;  src=M2; ks=fl>>4; ct=fl&15; dh=M2h+(size_t)fl*512; dl=M2l+(size_t)fl*512; }
  else              { int fl=f-192; src=M3; ks=fl>>4; ct=fl&15; dh=M3h+(size_t)fl*512; dl=M3l+(size_t)fl*512; }
  unsigned ph[4], pl[4];
#pragma unroll
  for (int p = 0; p < 4; ++p) {
    int k0 = ks*32 + khalf*8 + 2*p;
    float x0 = src[(size_t)k0*NHM     + ct*16 + col];
    float x1 = src[(size_t)(k0+1)*NHM + ct*16 + col];
    u16 h0 = f2bf(x0), h1 = f2bf(x1);
    u16 l0 = f2bf(x0 - bf2f(h0)), l1 = f2bf(x1 - bf2f(h1));
    ph[p] = (unsigned)h0 | ((unsigned)h1 << 16);
    pl[p] = (unsigned)l0 | ((unsigned)l1 << 16);
  }
  *(uint4*)(dh + lane*8) = make_uint4(ph[0], ph[1], ph[2], ph[3]);
  *(uint4*)(dl + lane*8) = make_uint4(pl[0], pl[1], pl[2], pl[3]);
}

#define CONV_FRAG(PTR, AH, AL) {                                        \
    const float* p_ = (PTR);                                            \
    float4 u0_ = *(const float4*)p_, u1_ = *(const float4*)(p_+4);      \
    float xv_[8] = {u0_.x,u0_.y,u0_.z,u0_.w,u1_.x,u1_.y,u1_.z,u1_.w};   \
    union { unsigned u[4]; short8 s; } H_, L_;                          \
    _Pragma("unroll")                                                   \
    for (int q_ = 0; q_ < 4; ++q_) {                                    \
      u16 h0_ = f2bf(xv_[2*q_]), h1_ = f2bf(xv_[2*q_+1]);               \
      u16 l0_ = f2bf(xv_[2*q_] - bf2f(h0_));                            \
      u16 l1_ = f2bf(xv_[2*q_+1] - bf2f(h1_));                          \
      H_.u[q_] = (unsigned)h0_ | ((unsigned)h1_ << 16);                 \
      L_.u[q_] = (unsigned)l0_ | ((unsigned)l1_ << 16);                 \
    }                                                                   \
    AH = H_.s; AL = L_.s; }

// store one f32 value as hi/lo bf16 pair into actH/actL at index IDX
#define PUT_HL(IDX, F) { float f_ = (F); u16 h_ = f2bf(f_);             \
    actH[IDX] = h_; actL[IDX] = f2bf(f_ - bf2f(h_)); }

// ---------- kernel 3: MFMA expert SIREN MLP + LN + Q-proj ----------
// (R20: activations stored in LDS as pre-packed bf16 hi/lo.)
__global__ __launch_bounds__(256) void k_expert(
    const float* __restrict__ pe,
    const u16* __restrict__ We1h, const u16* __restrict__ We1l,
    const u16* __restrict__ We2h, const u16* __restrict__ We2l,
    const u16* __restrict__ We3h, const u16* __restrict__ We3l,
    const u16* __restrict__ Wqh,  const u16* __restrict__ Wql,
    const float* __restrict__ be1, const float* __restrict__ be2,
    const float* __restrict__ be3,
    const float* __restrict__ ln_g, const float* __restrict__ ln_b,
    const int* __restrict__ plist, const int* __restrict__ cnt,
    float* __restrict__ featsC, float* __restrict__ QC)
{
  int e = blockIdx.y;
  int count = cnt[e];
  int base = blockIdx.x * 32;
  if (base >= count) return;
  __shared__ u16 actH[16*512];   // 16 KB
  __shared__ u16 actL[16*512];   // 16 KB
  __shared__ float lnS[256];
  __shared__ int pts[32];
  int tid = threadIdx.x;
  int w = tid >> 6, lane = tid & 63;
  int rloc = lane & 15, khalf = lane >> 4;

  if (tid < 32) {
    int slot = base + tid;
    pts[tid] = (slot < count) ? plist[e*NPTS + slot] : 0;
  } else if (tid >= 64 && tid < 192) {
    int i = tid - 64;
    lnS[i] = ln_g[i];
    lnS[128 + i] = ln_b[i];
  }
  __syncthreads();
  {
    int Mt = tid >> 7, ks = (tid >> 6) & 1;
    const float* src = pe + (size_t)pts[Mt*16 + rloc]*64 + ks*32 + khalf*8;
    float4 a = *(const float4*)src;
    float4 b = *(const float4*)(src + 4);
    float xv[8] = {a.x,a.y,a.z,a.w,b.x,b.y,b.z,b.w};
    unsigned ph[4], pl[4];
#pragma unroll
    for (int q = 0; q < 4; ++q) {
      u16 h0 = f2bf(xv[2*q]), h1 = f2bf(xv[2*q+1]);
      u16 l0 = f2bf(xv[2*q] - bf2f(h0)), l1 = f2bf(xv[2*q+1] - bf2f(h1));
      ph[q] = (unsigned)h0 | ((unsigned)h1 << 16);
      pl[q] = (unsigned)l0 | ((unsigned)l1 << 16);
    }
    int idx = (Mt*8 + ks)*512 + lane*8;
    *(uint4*)&actH[idx] = make_uint4(ph[0], ph[1], ph[2], ph[3]);
    *(uint4*)&actL[idx] = make_uint4(pl[0], pl[1], pl[2], pl[3]);
  }
  __syncthreads();

  // ---- L1: K=64 (2 ks), N=256, sin(30x) ----
  {
    f32x4 acc[2][4];
#pragma unroll
    for (int Mt = 0; Mt < 2; ++Mt)
#pragma unroll
      for (int c = 0; c < 4; ++c) acc[Mt][c] = (f32x4){0.f,0.f,0.f,0.f};
    for (int ks = 0; ks < 2; ++ks) {
      short8 ah[2], al[2];
#pragma unroll
      for (int Mt = 0; Mt < 2; ++Mt) {
        int idx = (Mt*8+ks)*512 + lane*8;
        ah[Mt] = *(const short8*)&actH[idx];
        al[Mt] = *(const short8*)&actL[idx];
      }
#pragma unroll
      for (int c = 0; c < 4; ++c) {
        size_t fo = ((size_t)e*32 + ks*16 + w*4 + c)*512 + (size_t)lane*8;
        short8 bh = *(const short8*)(We1h + fo);
        short8 bl = *(const short8*)(We1l + fo);
#pragma unroll
        for (int Mt = 0; Mt < 2; ++Mt) {
          acc[Mt][c] = __builtin_amdgcn_mfma_f32_16x16x32_bf16(ah[Mt], bh, acc[Mt][c], 0,0,0);
          acc[Mt][c] = __builtin_amdgcn_mfma_f32_16x16x32_bf16(ah[Mt], bl, acc[Mt][c], 0,0,0);
          acc[Mt][c] = __builtin_amdgcn_mfma_f32_16x16x32_bf16(al[Mt], bh, acc[Mt][c], 0,0,0);
        }
      }
    }
    __syncthreads();
#pragma unroll
    for (int Mt = 0; Mt < 2; ++Mt)
#pragma unroll
      for (int c = 0; c < 4; ++c) {
        int n = (w*4+c)*16 + rloc;
        float b = be1[e*NHE + n];
        int ksp = n >> 5, lp = ((n>>3)&3)*16, jp = n & 7;
#pragma unroll
        for (int i = 0; i < 4; ++i) {
          int idx = (Mt*8+ksp)*512 + (lp + khalf*4 + i)*8 + jp;
          PUT_HL(idx, sinf(30.f*(acc[Mt][c][i] + b)));
        }
      }
    __syncthreads();
  }

  // ---- L2: K=256 (8 ks), N=256, sin(30x) ----
  {
    f32x4 acc[2][4];
#pragma unroll
    for (int Mt = 0; Mt < 2; ++Mt)
#pragma unroll
      for (int c = 0; c < 4; ++c) acc[Mt][c] = (f32x4){0.f,0.f,0.f,0.f};
#pragma unroll 2
    for (int ks = 0; ks < 8; ++ks) {
      short8 ah[2], al[2];
#pragma unroll
      for (int Mt = 0; Mt < 2; ++Mt) {
        int idx = (Mt*8+ks)*512 + lane*8;
        ah[Mt] = *(const short8*)&actH[idx];
        al[Mt] = *(const short8*)&actL[idx];
      }
#pragma unroll
      for (int c = 0; c < 4; ++c) {
        size_t fo = ((size_t)e*128 + ks*16 + w*4 + c)*512 + (size_t)lane*8;
        short8 bh = *(const short8*)(We2h + fo);
        short8 bl = *(const short8*)(We2l + fo);
#pragma unroll
        for (int Mt = 0; Mt < 2; ++Mt) {
          acc[Mt][c] = __builtin_amdgcn_mfma_f32_16x16x32_bf16(ah[Mt], bh, acc[Mt][c], 0,0,0);
          acc[Mt][c] = __builtin_amdgcn_mfma_f32_16x16x32_bf16(ah[Mt], bl, acc[Mt][c], 0,0,0);
          acc[Mt][c] = __builtin_amdgcn_mfma_f32_16x16x32_bf16(al[Mt], bh, acc[Mt][c], 0,0,0);
        }
      }
    }
    __syncthreads();
#pragma unroll
    for (int Mt = 0; Mt < 2; ++Mt)
#pragma unroll
      for (int c = 0; c < 4; ++c) {
        int n = (w*4+c)*16 + rloc;
        float b = be2[e*NHE + n];
        int ksp = n >> 5, lp = ((n>>3)&3)*16, jp = n & 7;
#pragma unroll
        for (int i = 0; i < 4; ++i) {
          int idx = (Mt*8+ksp)*512 + (lp + khalf*4 + i)*8 + jp;
          PUT_HL(idx, sinf(30.f*(acc[Mt][c][i] + b)));
        }
      }
    __syncthreads();
  }

  // ---- L3: K=256 (8 ks), N=128, linear -> feats ----
  {
    f32x4 acc[2][2];
#pragma unroll
    for (int Mt = 0; Mt < 2; ++Mt)
#pragma unroll
      for (int c = 0; c < 2; ++c) acc[Mt][c] = (f32x4){0.f,0.f,0.f,0.f};
#pragma unroll 2
    for (int ks = 0; ks < 8; ++ks) {
      short8 ah[2], al[2];
#pragma unroll
      for (int Mt = 0; Mt < 2; ++Mt) {
        int idx = (Mt*8+ks)*512 + lane*8;
        ah[Mt] = *(const short8*)&actH[idx];
        al[Mt] = *(const short8*)&actL[idx];
      }
#pragma unroll
      for (int c = 0; c < 2; ++c) {
        size_t fo = ((size_t)e*64 + ks*8 + w*2 + c)*512 + (size_t)lane*8;
        short8 bh = *(const short8*)(We3h + fo);
        short8 bl = *(const short8*)(We3l + fo);
#pragma unroll
        for (int Mt = 0; Mt < 2; ++Mt) {
          acc[Mt][c] = __builtin_amdgcn_mfma_f32_16x16x32_bf16(ah[Mt], bh, acc[Mt][c], 0,0,0);
          acc[Mt][c] = __builtin_amdgcn_mfma_f32_16x16x32_bf16(ah[Mt], bl, acc[Mt][c], 0,0,0);
          acc[Mt][c] = __builtin_amdgcn_mfma_f32_16x16x32_bf16(al[Mt], bh, acc[Mt][c], 0,0,0);
        }
      }
    }
    __syncthreads();
#pragma unroll
    for (int Mt = 0; Mt < 2; ++Mt)
#pragma unroll
      for (int c = 0; c < 2; ++c) {
        int n = (w*2+c)*16 + rloc;
        float b = be3[e*DD + n];
        int ksp = n >> 5, lp = ((n>>3)&3)*16, jp = n & 7;
#pragma unroll
        for (int i = 0; i < 4; ++i) {
          float f = acc[Mt][c][i] + b;
          int idx = (Mt*8+ksp)*512 + (lp + khalf*4 + i)*8 + jp;
          PUT_HL(idx, f);
          int slot = base + Mt*16 + khalf*4 + i;
          if (slot < count)
            featsC[((size_t)e*NPTS + slot)*DD + n] = f;
        }
      }
    __syncthreads();
  }

  // ---- LN + Wq: K=128 (4 ks), N=128 ----
  {
    float mu[2], rsv[2];
#pragma unroll
    for (int Mt = 0; Mt < 2; ++Mt) {
      float sm = 0.f, sq = 0.f;
#pragma unroll
      for (int ks = 0; ks < 4; ++ks) {
        int idx = (Mt*8+ks)*512 + lane*8;
        short8 hv = *(const short8*)&actH[idx];
        short8 lv = *(const short8*)&actL[idx];
#pragma unroll
        for (int j = 0; j < 8; ++j) {
          float xx = bf2f((u16)hv[j]) + bf2f((u16)lv[j]);
          sm += xx; sq += xx*xx;
        }
      }
      sm += __shfl_xor(sm, 16); sq += __shfl_xor(sq, 16);
      sm += __shfl_xor(sm, 32); sq += __shfl_xor(sq, 32);
      mu[Mt] = sm * (1.f/128.f);
      rsv[Mt] = rsqrtf(sq * (1.f/128.f) - mu[Mt]*mu[Mt] + 1e-5f);
    }
    f32x4 acc[2][2];
#pragma unroll
    for (int Mt = 0; Mt < 2; ++Mt)
#pragma unroll
      for (int c = 0; c < 2; ++c) acc[Mt][c] = (f32x4){0.f,0.f,0.f,0.f};
    for (int ks = 0; ks < 4; ++ks) {
      short8 ah[2], al[2];
#pragma unroll
      for (int Mt = 0; Mt < 2; ++Mt) {
        int idx = (Mt*8+ks)*512 + lane*8;
        short8 hv = *(const short8*)&actH[idx];
        short8 lv = *(const short8*)&actL[idx];
        float xv[8];
#pragma unroll
        for (int j = 0; j < 8; ++j)
          xv[j] = bf2f((u16)hv[j]) + bf2f((u16)lv[j]);
        union { unsigned u[4]; short8 s; } H, L;
#pragma unroll
        for (int j = 0; j < 8; ++j) {
          int k = ks*32 + khalf*8 + j;
          xv[j] = (xv[j] - mu[Mt]) * rsv[Mt] * lnS[k] + lnS[128 + k];
        }
#pragma unroll
        for (int q = 0; q < 4; ++q) {
          u16 h0 = f2bf(xv[2*q]), h1 = f2bf(xv[2*q+1]);
          u16 l0 = f2bf(xv[2*q] - bf2f(h0)), l1 = f2bf(xv[2*q+1] - bf2f(h1));
          H.u[q] = (unsigned)h0 | ((unsigned)h1 << 16);
          L.u[q] = (unsigned)l0 | ((unsigned)l1 << 16);
        }
        ah[Mt] = H.s; al[Mt] = L.s;
      }
#pragma unroll
      for (int c = 0; c < 2; ++c) {
        size_t fo = ((size_t)e*32 + ks*8 + w*2 + c)*512 + (size_t)lane*8;
        short8 bh = *(const short8*)(Wqh + fo);
        short8 bl = *(const short8*)(Wql + fo);
#pragma unroll
        for (int Mt = 0; Mt < 2; ++Mt) {
          acc[Mt][c] = __builtin_amdgcn_mfma_f32_16x16x32_bf16(ah[Mt], bh, acc[Mt][c], 0,0,0);
          acc[Mt][c] = __builtin_amdgcn_mfma_f32_16x16x32_bf16(ah[Mt], bl, acc[Mt][c], 0,0,0);
          acc[Mt][c] = __builtin_amdgcn_mfma_f32_16x16x32_bf16(al[Mt], bh, acc[Mt][c], 0,0,0);
        }
      }
    }
#pragma unroll
    for (int Mt = 0; Mt < 2; ++Mt)
#pragma unroll
      for (int c = 0; c < 2; ++c) {
        int n = (w*2+c)*16 + rloc;
#pragma unroll
        for (int i = 0; i < 4; ++i) {
          int slot = base + Mt*16 + khalf*4 + i;
          if (slot < count)
            QC[((size_t)e*NPTS + slot)*DD + n] = acc[Mt][c][i];
        }
      }
  }
}

// ---------- kernel 4: MFMA scores -> LDS score matrix -> register top-16 ----------
// R23: REVERT to R18/R21 form (512 threads, 16 slots, 66 KB, 2 blocks/CU).
// R22's 1024-thread K-frag-reuse variant regressed 117->151us: losing the
// cross-block phase1/phase2 overlap (1 block/CU) cost more than halving L2
// K-traffic saved. Structural plateau: p1 L2-bound, p2 shuffle-latency-bound.
__global__ __launch_bounds__(512) void k_scores(
    const float* __restrict__ QC, const u16* __restrict__ Khf,
    const int* __restrict__ cnt,
    float* __restrict__ attnW, int* __restrict__ attnI)
{
  int e = blockIdx.y;
  int count = cnt[e];
  int sbase = blockIdx.x * 16;
  if (sbase >= count) return;
  __shared__ u16 Sall[16*2056];   // [slot][key], padded row
  int tid = threadIdx.x;
  int w = tid >> 6, lane = tid & 63;
  int rloc = lane & 15, khalf = lane >> 4;

  // Q B-frags in registers (same 16 slots for all waves)
  short8 qf[4];
  {
    int slot = sbase + rloc;
    const float* Qr = QC + ((size_t)e*NPTS + slot)*DD + khalf*8;
#pragma unroll
    for (int kt = 0; kt < 4; ++kt) {
      float q[8];
      if (slot < count) {
#pragma unroll
        for (int i = 0; i < 8; ++i) q[i] = Qr[kt*32 + i];
      } else {
#pragma unroll
        for (int i = 0; i < 8; ++i) q[i] = 0.f;
      }
      union { u16 h[8]; short8 s; } U;
#pragma unroll
      for (int i = 0; i < 8; ++i) U.h[i] = f2bf(q[i]);
      qf[kt] = U.s;
    }
  }

  // ---- phase 1: all 2048 keys; wave w does key-tiles it*8+w ----
  const u16* KhB = Khf + (size_t)e*128*4*512 + (size_t)lane*8;
  for (int it = 0; it < 16; ++it) {
    int T = it*8 + w;
    f32x4 acc = {0.f, 0.f, 0.f, 0.f};
#pragma unroll
    for (int kt = 0; kt < 4; ++kt) {
      short8 kf = *(const short8*)(KhB + ((size_t)T*4 + kt)*512);
      acc = __builtin_amdgcn_mfma_f32_16x16x32_bf16(kf, qf[kt], acc, 0, 0, 0);
    }
    union { u16 h[4]; ushort4 v; } P;
#pragma unroll
    for (int i = 0; i < 4; ++i) P.h[i] = bf2mono(f2bf(acc[i]));
    *(ushort4*)&Sall[(size_t)rloc*2056 + T*16 + khalf*4] = P.v;
  }
  __syncthreads();

  // ---- phase 2: wave w handles slots w*2 .. w*2+1, 2-wide interleaved ----
  const float inv_scale = 0.08838834764831845f;  // 1/sqrt(128)
#define INS4S(SL, P) { unsigned P_ = (P); if (P_ > p3[SL]) { p3[SL] = P_;       \
      if (p3[SL] > p2[SL]) { unsigned t_=p2[SL]; p2[SL]=p3[SL]; p3[SL]=t_; }    \
      if (p2[SL] > p1[SL]) { unsigned t_=p1[SL]; p1[SL]=p2[SL]; p2[SL]=t_; }    \
      if (p1[SL] > p0[SL]) { unsigned t_=p0[SL]; p0[SL]=p1[SL]; p1[SL]=t_; } } }

  {
    const u16* Srow[2];
    unsigned p0[2], p1[2], p2[2], p3[2];
#pragma unroll
    for (int sl = 0; sl < 2; ++sl) {
      Srow[sl] = &Sall[(size_t)(w*2 + sl)*2056];
      p0[sl] = p1[sl] = p2[sl] = p3[sl] = 0;
    }
    // interleaved candidate build: 2 rows' loads in flight together
#pragma unroll
    for (int i = 0; i < 16; ++i) {
      int k0 = lane*2 + i*128;
      unsigned cw[2];
#pragma unroll
      for (int sl = 0; sl < 2; ++sl)
        cw[sl] = *(const unsigned*)(Srow[sl] + k0);
#pragma unroll
      for (int sl = 0; sl < 2; ++sl) {
        unsigned P0 = ((cw[sl] & 0xFFFFu) << 11) | (unsigned)(2047 - k0);
        unsigned P1 = ((cw[sl] >> 16) << 11)     | (unsigned)(2047 - (k0+1));
        INS4S(sl, P0);
        INS4S(sl, P1);
      }
    }
    // 16 extraction rounds, 2 independent reduce chains per round
    unsigned keepP[2] = {0, 0};
    int popped[2] = {0, 0};
#pragma unroll 1
    for (int r = 0; r < 16; ++r) {
      unsigned m[2];
#pragma unroll
      for (int sl = 0; sl < 2; ++sl) m[sl] = p0[sl];
#pragma unroll
      for (int d = 1; d < 64; d <<= 1) {
#pragma unroll
        for (int sl = 0; sl < 2; ++sl) {
          unsigned o = __shfl_xor(m[sl], d);
          m[sl] = (o > m[sl]) ? o : m[sl];
        }
      }
#pragma unroll
      for (int sl = 0; sl < 2; ++sl) {
        if (lane == r) keepP[sl] = m[sl];
        if (p0[sl] == m[sl]) {   // unique winner (key embedded in packed value)
          p0[sl] = p1[sl]; p1[sl] = p2[sl]; p2[sl] = p3[sl]; p3[sl] = 0;
          if (++popped[sl] == 4) {
            // exact fallback: rebuild top-4 among remaining (< m strictly)
            p0[sl] = p1[sl] = p2[sl] = p3[sl] = 0;
            for (int i2 = 0; i2 < 16; ++i2) {
              int k0 = lane*2 + i2*128;
              unsigned cw = *(const unsigned*)(Srow[sl] + k0);
              unsigned P0 = ((cw & 0xFFFFu) << 11) | (unsigned)(2047 - k0);
              unsigned P1 = ((cw >> 16) << 11)     | (unsigned)(2047 - (k0+1));
              if (P0 < m[sl]) INS4S(sl, P0);
              if (P1 < m[sl]) INS4S(sl, P1);
            }
            popped[sl] = 0;
          }
        }
      }
    }
    // unpack + softmax + write (per slot; cheap)
#pragma unroll
    for (int sl = 0; sl < 2; ++sl) {
      int slot = sbase + w*2 + sl;
      if (slot >= count) continue;
      int keyv = 2047 - (int)(keepP[sl] & 0x7FFu);
      float val = bf2f(mono2bf((u16)(keepP[sl] >> 11)));
      float m0 = __shfl(val, 0);
      float ev = expf((val - m0) * inv_scale);
      float sum = ev;
      sum += __shfl_xor(sum, 1); sum += __shfl_xor(sum, 2);
      sum += __shfl_xor(sum, 4); sum += __shfl_xor(sum, 8);
      if (lane < 16) {
        size_t off = ((size_t)e*NPTS + slot)*NTK + lane;
        attnW[off] = ev / sum;
        attnI[off] = keyv;
      }
    }
  }
#undef INS4S
}

// ---------- kernel 5: MFMA adapter MLP + LN + attention combine ----------
// (R19: VA1 precompute; ainV out of LDS; 37.5 KB -> 4 blocks/CU.)
__global__ __launch_bounds__(256) void k_adapter(
    const float* __restrict__ Vhat, const float* __restrict__ pf,
    const float* __restrict__ VA1,
    const u16* __restrict__ A1h, const u16* __restrict__ A1l,
    const u16* __restrict__ A2h, const u16* __restrict__ A2l,
    const float* __restrict__ a1, const float* __restrict__ a2,
    const float* __restrict__ alng, const float* __restrict__ alnb,
    const float* __restrict__ attnW, const int* __restrict__ attnI,
    const float* __restrict__ featsC, const float* __restrict__ slotW,
    const int* __restrict__ plist, const int* __restrict__ cnt,
    float* __restrict__ outC)
{
  int e = blockIdx.y;
  int count = cnt[e];
  int s0 = blockIdx.x * 4;
  if (s0 >= count) return;
  __shared__ float hid[64][68];
  __shared__ float vaS[64][68];
  __shared__ float pfS[4][68];
  __shared__ float attwS[4][16];
  __shared__ float alnS[128], albS[128];
  __shared__ int   rtiS[64];
  __shared__ float wslS[4];
  __shared__ int   ptlS[4];
  int tid = threadIdx.x;
  if (tid < 64) {
    int sl = tid >> 4, key = tid & 15;
    int slot = s0 + sl;
    if (slot < count) {
      size_t o = ((size_t)e*NPTS + slot)*NTK + key;
      rtiS[tid] = attnI[o];
      attwS[sl][key] = attnW[o];
    } else { rtiS[tid] = 0; attwS[sl][key] = 0.f; }
  } else if (tid < 68) {
    int sl = tid - 64;
    int slot = s0 + sl;
    wslS[sl] = (slot < count) ? slotW[e*NPTS + slot] : 0.f;
    ptlS[sl] = (slot < count) ? plist[e*NPTS + slot] : 0;
  } else if (tid >= 128 && tid < 192) {
    int c2 = (tid - 128) * 2;
    alnS[c2]   = alng[e*DD + c2];
    alnS[c2+1] = alng[e*DD + c2+1];
    albS[c2]   = alnb[e*DD + c2];
    albS[c2+1] = alnb[e*DD + c2+1];
  }
  __syncthreads();
  // stage VA1 rows (64 x 64 f32) + pf rows
  for (int idx = tid; idx < 64*16; idx += 256) {
    int r = idx >> 4, c4 = (idx & 15) * 4;
    *(float4*)&vaS[r][c4] = *(const float4*)(VA1 + ((size_t)e*NM + rtiS[r])*64 + c4);
  }
  if (tid < 64) {
    int sl = tid >> 4, c4 = (tid & 15) * 4;
    *(float4*)&pfS[sl][c4] = *(const float4*)(pf + (size_t)ptlS[sl]*64 + c4);
  }
  __syncthreads();

  int w = tid >> 6, lane = tid & 63;
  int rloc = lane & 15;
  int khalf = lane >> 4;

  // ---- L1 (pf part only): K=64 (A1 frag ks=4,5), N=64 ----
  f32x4 acc1[4];
#pragma unroll
  for (int ct = 0; ct < 4; ++ct) acc1[ct] = (f32x4){0.f, 0.f, 0.f, 0.f};
  for (int ks = 4; ks < 6; ++ks) {
    short8 ah, al;
    CONV_FRAG(&pfS[w][(ks-4)*32 + khalf*8], ah, al);
    const u16* bh0 = A1h + ((size_t)e*24 + ks*4)*512 + (size_t)lane*8;
    const u16* bl0 = A1l + ((size_t)e*24 + ks*4)*512 + (size_t)lane*8;
#pragma unroll
    for (int ct = 0; ct < 4; ++ct) {
      short8 bh = *(const short8*)(bh0 + ct*512);
      short8 bl = *(const short8*)(bl0 + ct*512);
      acc1[ct] = __builtin_amdgcn_mfma_f32_16x16x32_bf16(ah, bh, acc1[ct], 0, 0, 0);
      acc1[ct] = __builtin_amdgcn_mfma_f32_16x16x32_bf16(ah, bl, acc1[ct], 0, 0, 0);
      acc1[ct] = __builtin_amdgcn_mfma_f32_16x16x32_bf16(al, bh, acc1[ct], 0, 0, 0);
    }
  }
#pragma unroll
  for (int ct = 0; ct < 4; ++ct) {
    float b = a1[e*64 + ct*16 + rloc];
#pragma unroll
    for (int i = 0; i < 4; ++i) {
      int row = w*16 + khalf*4 + i;
      hid[row][ct*16 + rloc] = fmaxf(acc1[ct][i] + b + vaS[row][ct*16 + rloc], 0.f);
    }
  }

  f32x4 acc2[8];
#pragma unroll
  for (int ct = 0; ct < 8; ++ct) acc2[ct] = (f32x4){0.f, 0.f, 0.f, 0.f};
  for (int ks = 0; ks < 2; ++ks) {
    short8 ah, al;
    CONV_FRAG(&hid[w*16 + rloc][ks*32 + khalf*8], ah, al);
    const u16* bh0 = A2h + ((size_t)e*16 + ks*8)*512 + (size_t)lane*8;
    const u16* bl0 = A2l + ((size_t)e*16 + ks*8)*512 + (size_t)lane*8;
#pragma unroll
    for (int ct = 0; ct < 8; ++ct) {
      short8 bh = *(const short8*)(bh0 + ct*512);
      short8 bl = *(const short8*)(bl0 + ct*512);
      acc2[ct] = __builtin_amdgcn_mfma_f32_16x16x32_bf16(ah, bh, acc2[ct], 0, 0, 0);
      acc2[ct] = __builtin_amdgcn_mfma_f32_16x16x32_bf16(ah, bl, acc2[ct], 0, 0, 0);
      acc2[ct] = __builtin_amdgcn_mfma_f32_16x16x32_bf16(al, bh, acc2[ct], 0, 0, 0);
    }
  }

  float ad[8][4];
#pragma unroll
  for (int ct = 0; ct < 8; ++ct) {
    float b = a2[e*DD + ct*16 + rloc];
#pragma unroll
    for (int i = 0; i < 4; ++i) ad[ct][i] = acc2[ct][i] + b;
  }
  float mu[4], rsv[4];
#pragma unroll
  for (int i = 0; i < 4; ++i) {
    float sm = 0.f, sq = 0.f;
#pragma unroll
    for (int ct = 0; ct < 8; ++ct) { sm += ad[ct][i]; sq += ad[ct][i]*ad[ct][i]; }
    sm += __shfl_xor(sm, 1); sq += __shfl_xor(sq, 1);
    sm += __shfl_xor(sm, 2); sq += __shfl_xor(sq, 2);
    sm += __shfl_xor(sm, 4); sq += __shfl_xor(sq, 4);
    sm += __shfl_xor(sm, 8); sq += __shfl_xor(sq, 8);
    mu[i] = sm * (1.f/128.f);
    float var = sq * (1.f/128.f) - mu[i]*mu[i];
    rsv[i] = rsqrtf(var + 1e-5f);
  }
  float aw[4];
#pragma unroll
  for (int i = 0; i < 4; ++i) aw[i] = attwS[w][khalf*4 + i];

  // combine: vt read direct from global (each element exactly once per block)
  const float* vrow[4];
#pragma unroll
  for (int i = 0; i < 4; ++i)
    vrow[i] = Vhat + ((size_t)e*NM + rtiS[w*16 + khalf*4 + i])*DD;

  float outv[8];
#pragma unroll
  for (int ct = 0; ct < 8; ++ct) {
    int cg = ct*16 + rloc;
    float g = alnS[cg], bb = albS[cg];
    float s = 0.f;
#pragma unroll
    for (int i = 0; i < 4; ++i) {
      float vt = vrow[i][cg];
      s += aw[i] * (vt + (ad[ct][i] - mu[i]) * rsv[i] * g + bb);
    }
    outv[ct] = s;
  }
#pragma unroll
  for (int ct = 0; ct < 8; ++ct) {
    outv[ct] += __shfl_xor(outv[ct], 16);
    outv[ct] += __shfl_xor(outv[ct], 32);
  }
  int slot = s0 + w;
  if (khalf == 0 && slot < count) {
    size_t o = ((size_t)e*NPTS + slot)*DD;
    float wg = wslS[w];
#pragma unroll
    for (int ct = 0; ct < 8; ++ct) {
      int cg = ct*16 + rloc;
      outC[o + cg] = wg * (outv[ct] + featsC[o + cg]);
    }
  }
}

// ---------- kernel 6: MFMA final MLP + sigmoid ----------
// (R21: actH/actL bf16 hi/lo packed activations.)
__global__ __launch_bounds__(256) void k_final(
    const float* __restrict__ outC, const int* __restrict__ pairE, const int* __restrict__ pairS,
    const u16* __restrict__ M1h, const u16* __restrict__ M1l,
    const u16* __restrict__ M2h, const u16* __restrict__ M2l,
    const u16* __restrict__ M3h, const u16* __restrict__ M3l,
    const float* __restrict__ c1, const float* __restrict__ c2,
    const float* __restrict__ c3,
    const float* __restrict__ M4, const float* __restrict__ c4,
    float* __restrict__ out)
{
  int base = blockIdx.x * 32;
  __shared__ u16 actH[16*512];   // 16 KB
  __shared__ u16 actL[16*512];   // 16 KB
  __shared__ float M4S[256];
  __shared__ int prE[64], prS[64];
  int tid = threadIdx.x;
  int w = tid >> 6, lane = tid & 63;
  int rloc = lane & 15, khalf = lane >> 4;

  if (tid < 64) {
    prE[tid] = pairE[(size_t)base*2 + tid];
    prS[tid] = pairS[(size_t)base*2 + tid];
  } else if (tid >= 64 && tid < 128) {
    int i = (tid - 64) * 4;
    *(float4*)&M4S[i] = *(const float4*)(M4 + i);
  }
  __syncthreads();
#pragma unroll
  for (int it = 0; it < 2; ++it) {
    int combo = it*4 + w;
    int Mt = combo >> 2, ks = combo & 3;
    int row = Mt*16 + rloc;
    const float* sA = outC + ((size_t)prE[row*2+0]*NPTS + prS[row*2+0])*DD + ks*32 + khalf*8;
    const float* sB = outC + ((size_t)prE[row*2+1]*NPTS + prS[row*2+1])*DD + ks*32 + khalf*8;
    float4 a0 = *(const float4*)sA, a1 = *(const float4*)(sA+4);
    float4 b0 = *(const float4*)sB, b1 = *(const float4*)(sB+4);
    float xv[8] = {a0.x+b0.x, a0.y+b0.y, a0.z+b0.z, a0.w+b0.w,
                   a1.x+b1.x, a1.y+b1.y, a1.z+b1.z, a1.w+b1.w};
    unsigned ph[4], pl[4];
#pragma unroll
    for (int q = 0; q < 4; ++q) {
      u16 h0 = f2bf(xv[2*q]), h1 = f2bf(xv[2*q+1]);
      u16 l0 = f2bf(xv[2*q] - bf2f(h0)), l1 = f2bf(xv[2*q+1] - bf2f(h1));
      ph[q] = (unsigned)h0 | ((unsigned)h1 << 16);
      pl[q] = (unsigned)l0 | ((unsigned)l1 << 16);
    }
    int idx = (Mt*8 + ks)*512 + lane*8;
    *(uint4*)&actH[idx] = make_uint4(ph[0], ph[1], ph[2], ph[3]);
    *(uint4*)&actL[idx] = make_uint4(pl[0], pl[1], pl[2], pl[3]);
  }
  __syncthreads();

  // ---- L1: K=128 (4 ks), N=256, relu ----
  {
    f32x4 acc[2][4];
#pragma unroll
    for (int Mt = 0; Mt < 2; ++Mt)
#pragma unroll
      for (int c = 0; c < 4; ++c) acc[Mt][c] = (f32x4){0.f,0.f,0.f,0.f};
    for (int ks = 0; ks < 4; ++ks) {
      short8 ah[2], al[2];
#pragma unroll
      for (int Mt = 0; Mt < 2; ++Mt) {
        int idx = (Mt*8+ks)*512 + lane*8;
        ah[Mt] = *(const short8*)&actH[idx];
        al[Mt] = *(const short8*)&actL[idx];
      }
#pragma unroll
      for (int c = 0; c < 4; ++c) {
        size_t fo = ((size_t)(ks*16 + w*4 + c))*512 + (size_t)lane*8;
        short8 bh = *(const short8*)(M1h + fo);
        short8 bl = *(const short8*)(M1l + fo);
#pragma unroll
        for (int Mt = 0; Mt < 2; ++Mt) {
          acc[Mt][c] = __builtin_amdgcn_mfma_f32_16x16x32_bf16(ah[Mt], bh, acc[Mt][c], 0,0,0);
          acc[Mt][c] = __builtin_amdgcn_mfma_f32_16x16x32_bf16(ah[Mt], bl, acc[Mt][c], 0,0,0);
          acc[Mt][c] = __builtin_amdgcn_mfma_f32_16x16x32_bf16(al[Mt], bh, acc[Mt][c], 0,0,0);
        }
      }
    }
    __syncthreads();
#pragma unroll
    for (int Mt = 0; Mt < 2; ++Mt)
#pragma unroll
      for (int c = 0; c < 4; ++c) {
        int n = (w*4+c)*16 + rloc;
        float b = c1[n];
        int ksp = n >> 5, lp = ((n>>3)&3)*16, jp = n & 7;
#pragma unroll
        for (int i = 0; i < 4; ++i) {
          int idx = (Mt*8+ksp)*512 + (lp + khalf*4 + i)*8 + jp;
          PUT_HL(idx, fmaxf(acc[Mt][c][i] + b, 0.f));
        }
      }
    __syncthreads();
  }

  // ---- L2, L3: K=256 (8 ks), N=256, relu ----
#pragma unroll 1
  for (int layer = 0; layer < 2; ++layer) {
    const u16* Wh = layer ? M3h : M2h;
    const u16* Wl = layer ? M3l : M2l;
    const float* bias = layer ? c3 : c2;
    f32x4 acc[2][4];
#pragma unroll
    for (int Mt = 0; Mt < 2; ++Mt)
#pragma unroll
      for (int c = 0; c < 4; ++c) acc[Mt][c] = (f32x4){0.f,0.f,0.f,0.f};
#pragma unroll 2
    for (int ks = 0; ks < 8; ++ks) {
      short8 ah[2], al[2];
#pragma unroll
      for (int Mt = 0; Mt < 2; ++Mt) {
        int idx = (Mt*8+ks)*512 + lane*8;
        ah[Mt] = *(const short8*)&actH[idx];
        al[Mt] = *(const short8*)&actL[idx];
      }
#pragma unroll
      for (int c = 0; c < 4; ++c) {
        size_t fo = ((size_t)(ks*16 + w*4 + c))*512 + (size_t)lane*8;
        short8 bh = *(const short8*)(Wh + fo);
        short8 bl = *(const short8*)(Wl + fo);
#pragma unroll
        for (int Mt = 0; Mt < 2; ++Mt) {
          acc[Mt][c] = __builtin_amdgcn_mfma_f32_16x16x32_bf16(ah[Mt], bh, acc[Mt][c], 0,0,0);
          acc[Mt][c] = __builtin_amdgcn_mfma_f32_16x16x32_bf16(ah[Mt], bl, acc[Mt][c], 0,0,0);
          acc[Mt][c] = __builtin_amdgcn_mfma_f32_16x16x32_bf16(al[Mt], bh, acc[Mt][c], 0,0,0);
        }
      }
    }
    __syncthreads();
#pragma unroll
    for (int Mt = 0; Mt < 2; ++Mt)
#pragma unroll
      for (int c = 0; c < 4; ++c) {
        int n = (w*4+c)*16 + rloc;
        float b = bias[n];
        int ksp = n >> 5, lp = ((n>>3)&3)*16, jp = n & 7;
#pragma unroll
        for (int i = 0; i < 4; ++i) {
          int idx = (Mt*8+ksp)*512 + (lp + khalf*4 + i)*8 + jp;
          PUT_HL(idx, fmaxf(acc[Mt][c][i] + b, 0.f));
        }
      }
    __syncthreads();
  }

  // ---- final: dot(row, M4) + c4 -> sigmoid; waves 0,1 handle Mt=w ----
  if (w < 2) {
    int Mt = w;
    float p = 0.f;
#pragma unroll
    for (int ks = 0; ks < 8; ++ks) {
      int idx = (Mt*8+ks)*512 + lane*8;
      short8 hv = *(const short8*)&actH[idx];
      short8 lv = *(const short8*)&actL[idx];
      const float* mm = &M4S[ks*32 + khalf*8];
#pragma unroll
      for (int j = 0; j < 8; ++j) {
        float xx = bf2f((u16)hv[j]) + bf2f((u16)lv[j]);
        p = fmaf(xx, mm[j], p);
      }
    }
    p += __shfl_xor(p, 16);
    p += __shfl_xor(p, 32);
    if (khalf == 0) {
      float z = p + c4[0];
      out[base + Mt*16 + rloc] = 1.f / (1.f + expf(-z));
    }
  }
}

// ---------- launcher ----------
extern "C" void kernel_launch(void* const* d_in, const int* in_sizes, int n_in,
                              void* d_out, int out_size, void* d_ws, size_t ws_size,
                              hipStream_t stream)
{
  const float* x    = (const float*)d_in[0];
  const float* lines= (const float*)d_in[1];
  const float* Wm1  = (const float*)d_in[2];
  const float* bm1  = (const float*)d_in[3];
  const float* Wm2  = (const float*)d_in[4];
  const float* bm2  = (const float*)d_in[5];
  const float* We1  = (const float*)d_in[6];
  const float* be1  = (const float*)d_in[7];
  const float* We2  = (const float*)d_in[8];
  const float* be2  = (const float*)d_in[9];
  const float* We3  = (const float*)d_in[10];
  const float* be3  = (const float*)d_in[11];
  const float* ln_g = (const float*)d_in[12];
  const float* ln_b = (const float*)d_in[13];
  const float* Wq   = (const float*)d_in[14];
  const float* Wk   = (const float*)d_in[15];
  const float* Wv   = (const float*)d_in[16];
  const float* A1   = (const float*)d_in[17];
  const float* a1   = (const float*)d_in[18];
  const float* A2   = (const float*)d_in[19];
  const float* a2   = (const float*)d_in[20];
  const float* alng = (const float*)d_in[21];
  const float* alnb = (const float*)d_in[22];
  const float* mem_k= (const float*)d_in[23];
  const float* mem_v= (const float*)d_in[24];
  const float* M1   = (const float*)d_in[25];
  const float* c1   = (const float*)d_in[26];
  const float* M2   = (const float*)d_in[27];
  const float* c2   = (const float*)d_in[28];
  const float* M3   = (const float*)d_in[29];
  const float* c3   = (const float*)d_in[30];
  const float* M4   = (const float*)d_in[31];
  const float* c4   = (const float*)d_in[32];
  float* out = (float*)d_out;

  char* wp = (char*)d_ws;
  auto alloc = [&](size_t bytes) -> void* {
    void* p = (void*)wp;
    wp += (bytes + 255) & ~(size_t)255;
    return p;
  };
  float* pf     = (float*)alloc((size_t)NPTS*64*4);
  float* pe     = (float*)alloc((size_t)NPTS*64*4);
  u16*   Khf    = (u16*)alloc((size_t)NE*128*4*512*2);   // bf16-hi K A-fragments
  u16*   We1h   = (u16*)alloc((size_t)NE*32*512*2);
  u16*   We1l   = (u16*)alloc((size_t)NE*32*512*2);
  u16*   We2h   = (u16*)alloc((size_t)NE*128*512*2);
  u16*   We2l   = (u16*)alloc((size_t)NE*128*512*2);
  u16*   We3h   = (u16*)alloc((size_t)NE*64*512*2);
  u16*   We3l   = (u16*)alloc((size_t)NE*64*512*2);
  u16*   Wqh    = (u16*)alloc((size_t)NE*32*512*2);
  u16*   Wql    = (u16*)alloc((size_t)NE*32*512*2);
  u16*   A1h    = (u16*)alloc((size_t)NE*24*512*2);
  u16*   A1l    = (u16*)alloc((size_t)NE*24*512*2);
  u16*   A2h    = (u16*)alloc((size_t)NE*16*512*2);
  u16*   A2l    = (u16*)alloc((size_t)NE*16*512*2);
  u16*   M1h    = (u16*)alloc((size_t)64*512*2);
  u16*   M1l    = (u16*)alloc((size_t)64*512*2);
  u16*   M2h    = (u16*)alloc((size_t)128*512*2);
  u16*   M2l    = (u16*)alloc((size_t)128*512*2);
  u16*   M3h    = (u16*)alloc((size_t)128*512*2);
  u16*   M3l    = (u16*)alloc((size_t)128*512*2);
  float* Vhat   = (float*)alloc((size_t)NE*NM*DD*4);
  float* VA1    = (float*)alloc((size_t)NE*NM*64*4);
  float* featsC = (float*)alloc((size_t)NE*NPTS*DD*4);
  float* QoutC  = (float*)alloc((size_t)NE*NPTS*DD*4);  // QC then reused as outC
  float* attnWb = (float*)alloc((size_t)NE*NPTS*NTK*4);
  float* slotW  = (float*)alloc((size_t)NE*NPTS*4);
  int*   attnIb = (int*)alloc((size_t)NE*NPTS*NTK*4);
  int*   plist  = (int*)alloc((size_t)NE*NPTS*4);
  int*   pairE  = (int*)alloc((size_t)NPTS*2*4);
  int*   pairS  = (int*)alloc((size_t)NPTS*2*4);
  int*   cnt    = (int*)alloc(64);

  hipMemsetAsync(cnt, 0, 64, stream);
  k_preproc<<<NPTS/256, 256, 0, stream>>>(x, lines, Wm1, bm1, Wm2, bm2,
                                          pf, pe, slotW, plist, pairE, pairS, cnt);
  k_kv<<<dim3(NM/32, NE, 2), 256, 0, stream>>>(mem_k, mem_v, Wk, Wv, Khf, Vhat);
  k_va1<<<dim3(NM/32, NE), 256, 0, stream>>>(Vhat, A1, VA1);
  k_pack<<<dim3(296, NE), 64, 0, stream>>>(We1, We2, We3, Wq, A1, A2,
                                           We1h, We1l, We2h, We2l,
                                           We3h, We3l, Wqh, Wql,
                                           A1h, A1l, A2h, A2l);
  k_packM<<<320, 64, 0, stream>>>(M1, M2, M3, M1h, M1l, M2h, M2l, M3h, M3l);
  k_expert<<<dim3(NPTS/32, NE), 256, 0, stream>>>(pe, We1h, We1l, We2h, We2l,
                                                  We3h, We3l, Wqh, Wql,
                                                  be1, be2, be3, ln_g, ln_b,
                                                  plist, cnt, featsC, QoutC);
  k_scores<<<dim3(NPTS/16, NE), 512, 0, stream>>>(QoutC, Khf, cnt, attnWb, attnIb);
  k_adapter<<<dim3(NPTS/4, NE), 256, 0, stream>>>(Vhat, pf, VA1, A1h, A1l, A2h, A2l,
                                                  a1, a2, alng, alnb,
                                                  attnWb, attnIb, featsC, slotW, plist, cnt,
                                                  QoutC);
  k_final<<<NPTS/32, 256, 0, stream>>>(QoutC, pairE, pairS,
                                       M1h, M1l, M2h, M2l, M3h, M3l,
                                       c1, c2, c3, M4, c4, out);
}